// Round 1
// baseline (29372.711 us; speedup 1.0000x reference)
//
#include <hip/hip_runtime.h>
#include <math.h>

// ---------------- problem constants ----------------
static constexpr int NB   = 64;           // batch
static constexpr int SS   = 197;          // tokens
static constexpr int DD   = 768;          // hidden
static constexpr int NHH  = 12;           // heads
static constexpr int DHH  = 64;           // head dim
static constexpr int FFF  = 3072;         // mlp hidden
static constexpr int TOK  = NB * SS;      // 12608
static constexpr int NPAT = 196;          // patches per image
static constexpr long NX  = (long)TOK * DD;  // 9,682,944

// ---------------- generic tiled fp32 GEMM ----------------
// C[m][n] = alpha * sum_k A[m][k] * B'[k][n]  (+bias[n]) (+residual) (gelu)
// TRANS_B: B' = Bm[n][k] (row-major N x K).  else B' = Bm[k][n] (row-major K x N)
// batch z: hi/lo split via innerB; base offsets = zhi*sXhi + zlo*sXlo
template<bool TRANS_B, int EPI>   // EPI: 0 none, 1 +residual, 2 gelu
__global__ __launch_bounds__(256) void gemm_tile(
    const float* __restrict__ A, int lda, long sAhi, long sAlo,
    const float* __restrict__ Bm, int ldb, long sBhi, long sBlo,
    float* __restrict__ Cm, int ldc, long sChi, long sClo,
    const float* __restrict__ bias, long sbhi, long sblo,
    const float* __restrict__ R, int ldr,
    int M, int N, int K, int innerB, float alpha)
{
    int z = blockIdx.z;
    int zhi = z / innerB, zlo = z - zhi * innerB;
    A  += zhi * sAhi + zlo * sAlo;
    Bm += zhi * sBhi + zlo * sBlo;
    Cm += zhi * sChi + zlo * sClo;
    if (bias) bias += zhi * sbhi + zlo * sblo;

    __shared__ float As[16][64];
    __shared__ float Bs[16][64];

    const int m0 = blockIdx.y * 64, n0 = blockIdx.x * 64;
    const int t = threadIdx.x;
    const int tm = (t & 15) * 4;
    const int tn = (t >> 4) * 4;

    const bool a4 = ((((uintptr_t)A)  & 15) == 0) && ((lda & 3) == 0);
    const bool b4 = ((((uintptr_t)Bm) & 15) == 0) && ((ldb & 3) == 0);

    float acc[4][4] = {};

    for (int k0 = 0; k0 < K; k0 += 16) {
        // ---- load A tile -> As[k][m]
        {
            int r  = t >> 2;          // 0..63 row in tile
            int kq = (t & 3) * 4;     // 0,4,8,12
            int gm = m0 + r;
            float av[4] = {0.f, 0.f, 0.f, 0.f};
            if (gm < M) {
                int kb = k0 + kq;
                if (a4 && (kb + 3 < K)) {
                    float4 v = *reinterpret_cast<const float4*>(&A[(long)gm * lda + kb]);
                    av[0] = v.x; av[1] = v.y; av[2] = v.z; av[3] = v.w;
                } else {
                    for (int u = 0; u < 4; ++u)
                        if (kb + u < K) av[u] = A[(long)gm * lda + kb + u];
                }
            }
            As[kq + 0][r] = av[0]; As[kq + 1][r] = av[1];
            As[kq + 2][r] = av[2]; As[kq + 3][r] = av[3];
        }
        // ---- load B tile -> Bs[k][n]
        if (TRANS_B) {
            int r  = t >> 2;          // n in tile
            int kq = (t & 3) * 4;
            int gn = n0 + r;
            float bv[4] = {0.f, 0.f, 0.f, 0.f};
            if (gn < N) {
                int kb = k0 + kq;
                if (b4 && (kb + 3 < K)) {
                    float4 v = *reinterpret_cast<const float4*>(&Bm[(long)gn * ldb + kb]);
                    bv[0] = v.x; bv[1] = v.y; bv[2] = v.z; bv[3] = v.w;
                } else {
                    for (int u = 0; u < 4; ++u)
                        if (kb + u < K) bv[u] = Bm[(long)gn * ldb + kb + u];
                }
            }
            Bs[kq + 0][r] = bv[0]; Bs[kq + 1][r] = bv[1];
            Bs[kq + 2][r] = bv[2]; Bs[kq + 3][r] = bv[3];
        } else {
            int kr = t >> 4;          // 0..15
            int nq = (t & 15) * 4;    // 0..60
            int gk = k0 + kr;
            float bv[4] = {0.f, 0.f, 0.f, 0.f};
            if (gk < K) {
                int nb = n0 + nq;
                if (b4 && (nb + 3 < N)) {
                    float4 v = *reinterpret_cast<const float4*>(&Bm[(long)gk * ldb + nb]);
                    bv[0] = v.x; bv[1] = v.y; bv[2] = v.z; bv[3] = v.w;
                } else {
                    for (int u = 0; u < 4; ++u)
                        if (nb + u < N) bv[u] = Bm[(long)gk * ldb + nb + u];
                }
            }
            Bs[kr][nq + 0] = bv[0]; Bs[kr][nq + 1] = bv[1];
            Bs[kr][nq + 2] = bv[2]; Bs[kr][nq + 3] = bv[3];
        }
        __syncthreads();
        #pragma unroll
        for (int kk = 0; kk < 16; ++kk) {
            float4 a = *reinterpret_cast<const float4*>(&As[kk][tm]);
            float4 b = *reinterpret_cast<const float4*>(&Bs[kk][tn]);
            float ar[4] = {a.x, a.y, a.z, a.w};
            float br[4] = {b.x, b.y, b.z, b.w};
            #pragma unroll
            for (int i = 0; i < 4; ++i)
                #pragma unroll
                for (int j = 0; j < 4; ++j)
                    acc[i][j] += ar[i] * br[j];
        }
        __syncthreads();
    }

    // ---- epilogue
    for (int i = 0; i < 4; ++i) {
        int gm = m0 + tm + i;
        if (gm >= M) continue;
        for (int j = 0; j < 4; ++j) {
            int gn = n0 + tn + j;
            if (gn >= N) continue;
            float v = acc[i][j] * alpha;
            if (bias) v += bias[gn];
            if (EPI == 1) v += R[(long)gm * ldr + gn];
            if (EPI == 2) v = 0.5f * v * (1.0f + erff(v * 0.70710678118654752f));
            Cm[(long)gm * ldc + gn] = v;
        }
    }
}

// ---------------- LayerNorm (row = one token, D=768) ----------------
__global__ __launch_bounds__(256) void ln_kernel(
    const float* __restrict__ X, const float* __restrict__ g,
    const float* __restrict__ b, float* __restrict__ H)
{
    const long row = blockIdx.x;
    const float* x = X + row * DD;
    const int t = threadIdx.x;
    float v[3];
    float s = 0.f, s2 = 0.f;
    #pragma unroll
    for (int i = 0; i < 3; ++i) {
        v[i] = x[t + i * 256];
        s += v[i]; s2 += v[i] * v[i];
    }
    #pragma unroll
    for (int off = 1; off < 64; off <<= 1) {
        s  += __shfl_xor(s,  off);
        s2 += __shfl_xor(s2, off);
    }
    __shared__ float red[2][4];
    const int lane = t & 63, w = t >> 6;
    if (lane == 0) { red[0][w] = s; red[1][w] = s2; }
    __syncthreads();
    float S1 = red[0][0] + red[0][1] + red[0][2] + red[0][3];
    float S2 = red[1][0] + red[1][1] + red[1][2] + red[1][3];
    float mu  = S1 * (1.0f / 768.0f);
    float var = S2 * (1.0f / 768.0f) - mu * mu;
    float rs  = rsqrtf(var + 1e-5f);
    float* h = H + row * DD;
    #pragma unroll
    for (int i = 0; i < 3; ++i) {
        int c = t + i * 256;
        h[c] = (v[i] - mu) * rs * g[c] + b[c];
    }
}

// ---------------- softmax over last dim (row length 197) ----------------
__global__ __launch_bounds__(64) void softmax_kernel(float* __restrict__ Sc)
{
    float* p = Sc + (long)blockIdx.x * SS;
    const int t = threadIdx.x;
    float vals[4];
    float mx = -1e30f;
    #pragma unroll
    for (int i = 0; i < 4; ++i) {
        int c = t + i * 64;
        vals[i] = (c < SS) ? p[c] : -1e30f;
        mx = fmaxf(mx, vals[i]);
    }
    #pragma unroll
    for (int off = 1; off < 64; off <<= 1) mx = fmaxf(mx, __shfl_xor(mx, off));
    float sum = 0.f;
    #pragma unroll
    for (int i = 0; i < 4; ++i) {
        int c = t + i * 64;
        if (c < SS) { vals[i] = expf(vals[i] - mx); sum += vals[i]; }
    }
    #pragma unroll
    for (int off = 1; off < 64; off <<= 1) sum += __shfl_xor(sum, off);
    float inv = 1.0f / sum;
    #pragma unroll
    for (int i = 0; i < 4; ++i) {
        int c = t + i * 64;
        if (c < SS) p[c] = vals[i] * inv;
    }
}

// ---------------- patchify: [B,C,H,W] -> [B*196, 768] ----------------
__global__ void patchify_kernel(const float* __restrict__ img, float* __restrict__ patches)
{
    long idx = (long)blockIdx.x * 256 + threadIdx.x;
    const long total = (long)NB * NPAT * DD;
    if (idx >= total) return;
    int k  = (int)(idx % DD);
    long mp = idx / DD;
    int p  = (int)(mp % NPAT);
    long b = mp / NPAT;
    int c = k >> 8;            // /256
    int i = (k >> 4) & 15;
    int j = k & 15;
    int pr = p / 14, pc = p % 14;
    int hh = pr * 16 + i, ww = pc * 16 + j;
    patches[idx] = img[((b * 3 + c) * 224 + hh) * 224 + ww];
}

// ---------------- assemble x = concat(cls, tokens) + pos ----------------
__global__ void assemble_kernel(const float* __restrict__ tok, const float* __restrict__ cls,
                                const float* __restrict__ pos, float* __restrict__ X)
{
    long idx = (long)blockIdx.x * 256 + threadIdx.x;
    if (idx >= NX) return;
    int d  = (int)(idx % DD);
    long bs = idx / DD;
    int s  = (int)(bs % SS);
    long b = bs / SS;
    float v = (s == 0) ? cls[d] : tok[(b * NPAT + s - 1) * DD + d];
    X[idx] = v + pos[(long)s * DD + d];
}

__global__ void copy_kernel(const float* __restrict__ src, float* __restrict__ dst, long n)
{
    long i = (long)blockIdx.x * 256 + threadIdx.x;
    if (i < n) dst[i] = src[i];
}

// ---------------- host ----------------
extern "C" void kernel_launch(void* const* d_in, const int* in_sizes, int n_in,
                              void* d_out, int out_size, void* d_ws, size_t ws_size,
                              hipStream_t stream)
{
    const float* images   = (const float*)d_in[0];
    const float* mapper_w = (const float*)d_in[1];
    const float* mapper_b = (const float*)d_in[2];
    const float* cls      = (const float*)d_in[3];
    const float* pos      = (const float*)d_in[4];
    const float* ln1_g    = (const float*)d_in[5];
    const float* ln1_b    = (const float*)d_in[6];
    const float* qw       = (const float*)d_in[7];
    const float* qb       = (const float*)d_in[8];
    const float* kw       = (const float*)d_in[9];
    const float* kb       = (const float*)d_in[10];
    const float* vw       = (const float*)d_in[11];
    const float* vb       = (const float*)d_in[12];
    const float* ow       = (const float*)d_in[13];
    const float* ob       = (const float*)d_in[14];
    const float* ln2_g    = (const float*)d_in[15];
    const float* ln2_b    = (const float*)d_in[16];
    const float* w1       = (const float*)d_in[17];
    const float* b1       = (const float*)d_in[18];
    const float* w2       = (const float*)d_in[19];
    const float* b2       = (const float*)d_in[20];
    float* out = (float*)d_out;

    float* ws = (float*)d_ws;
    float* x    = ws;
    float* h    = x + NX;
    float* q    = h + NX;      // also ctx
    float* kbuf = q + NX;
    float* v    = kbuf + NX;
    float* big  = v + NX;      // 38,731,776 floats: patches/tokens | attn | mid

    const long bigN = (long)TOK * FFF;
    size_t need = (size_t)(5 * NX + bigN) * sizeof(float);
    if (ws_size < need) return;

    float* patches = big;
    float* tokens  = big + 10000000;
    float* attn    = big;
    float* mid     = big;

    // ---- setup: patchify + mapper + assemble
    {
        long n = (long)NB * NPAT * DD;
        patchify_kernel<<<dim3((n + 255) / 256), dim3(256), 0, stream>>>(images, patches);
        // tokens = patches @ mapper_w^T + mapper_b   (M=12544, N=768, K=768)
        gemm_tile<true, 0><<<dim3(DD / 64, (NB * NPAT) / 64, 1), dim3(256), 0, stream>>>(
            patches, DD, 0, 0,
            mapper_w, DD, 0, 0,
            tokens, DD, 0, 0,
            mapper_b, 0, 0,
            nullptr, 0,
            NB * NPAT, DD, DD, 1, 1.0f);
        assemble_kernel<<<dim3((NX + 255) / 256), dim3(256), 0, stream>>>(tokens, cls, pos, x);
    }

    const long sQhi = (long)SS * DD;     // 151296: per-image stride in q/k/v/ctx
    const long sShi = (long)NHH * SS * SS; // 465708: per-image stride in scores
    const long sSlo = (long)SS * SS;       // 38809

    for (int l = 0; l < 12; ++l) {
        // LN1
        ln_kernel<<<dim3(TOK), dim3(256), 0, stream>>>(x, ln1_g + l * DD, ln1_b + l * DD, h);

        // QKV per-head: M=TOK, N=64, K=64, batch=12 heads
        const float* wv3[3] = { qw + (long)l * NHH * DHH * DHH,
                                kw + (long)l * NHH * DHH * DHH,
                                vw + (long)l * NHH * DHH * DHH };
        const float* bv3[3] = { qb + l * DD, kb + l * DD, vb + l * DD };
        float* ov3[3] = { q, kbuf, v };
        for (int c = 0; c < 3; ++c) {
            gemm_tile<true, 0><<<dim3(1, TOK / 64, NHH), dim3(256), 0, stream>>>(
                h, DD, 0, DHH,
                wv3[c], DHH, 0, (long)DHH * DHH,
                ov3[c], DD, 0, DHH,
                bv3[c], 0, DHH,
                nullptr, 0,
                TOK, DHH, DHH, NHH, 1.0f);
        }

        // scores = q k^T / 4096 : M=N=197, K=64, batch = 64*12
        gemm_tile<true, 0><<<dim3(4, 4, NB * NHH), dim3(256), 0, stream>>>(
            q, DD, sQhi, DHH,
            kbuf, DD, sQhi, DHH,
            attn, SS, sShi, sSlo,
            nullptr, 0, 0,
            nullptr, 0,
            SS, SS, DHH, NHH, 1.0f / 4096.0f);

        softmax_kernel<<<dim3(NB * NHH * SS), dim3(64), 0, stream>>>(attn);

        // ctx = attn @ v : M=197, N=64, K=197 (NN), write into q buffer
        gemm_tile<false, 0><<<dim3(1, 4, NB * NHH), dim3(256), 0, stream>>>(
            attn, SS, sShi, sSlo,
            v, DD, sQhi, DHH,
            q, DD, sQhi, DHH,
            nullptr, 0, 0,
            nullptr, 0,
            SS, DHH, SS, NHH, 1.0f);

        // x = x + ctx @ ow^T + ob
        gemm_tile<true, 1><<<dim3(DD / 64, TOK / 64, 1), dim3(256), 0, stream>>>(
            q, DD, 0, 0,
            ow + (long)l * DD * DD, DD, 0, 0,
            x, DD, 0, 0,
            ob + l * DD, 0, 0,
            x, DD,
            TOK, DD, DD, 1, 1.0f);

        // LN2
        ln_kernel<<<dim3(TOK), dim3(256), 0, stream>>>(x, ln2_g + l * DD, ln2_b + l * DD, h);

        // mid = gelu(h @ w1^T + b1) : N=3072
        gemm_tile<true, 2><<<dim3(FFF / 64, TOK / 64, 1), dim3(256), 0, stream>>>(
            h, DD, 0, 0,
            w1 + (long)l * FFF * DD, DD, 0, 0,
            mid, FFF, 0, 0,
            b1 + l * FFF, 0, 0,
            nullptr, 0,
            TOK, FFF, DD, 1, 1.0f);

        // x = x + mid @ w2^T + b2 : K=3072
        gemm_tile<true, 1><<<dim3(DD / 64, TOK / 64, 1), dim3(256), 0, stream>>>(
            mid, FFF, 0, 0,
            w2 + (long)l * DD * FFF, FFF, 0, 0,
            x, DD, 0, 0,
            b2 + l * DD, 0, 0,
            x, DD,
            TOK, DD, FFF, 1, 1.0f);

        // extract
        int slot = (l == 2) ? 0 : (l == 5) ? 1 : (l == 8) ? 2 : (l == 11) ? 3 : -1;
        if (slot >= 0) {
            copy_kernel<<<dim3((NX + 255) / 256), dim3(256), 0, stream>>>(
                x, out + (long)slot * NX, NX);
        }
    }
}

// Round 2
// 11295.985 us; speedup vs baseline: 2.6003x; 2.6003x over previous
//
#include <hip/hip_runtime.h>
#include <hip/hip_bf16.h>
#include <math.h>

// ---------------- problem constants ----------------
static constexpr int NB   = 64;           // batch
static constexpr int SS   = 197;          // tokens
static constexpr int DD   = 768;          // hidden
static constexpr int NHH  = 12;           // heads
static constexpr int DHH  = 64;           // head dim
static constexpr int FFF  = 3072;         // mlp hidden
static constexpr int TOK  = NB * SS;      // 12608
static constexpr int NPAT = 196;          // patches per image
static constexpr int PADM = 12672;        // TOK padded to multiple of 128
static constexpr long NX  = (long)TOK * DD;  // 9,682,944

typedef __attribute__((ext_vector_type(8))) short bf16x8;
typedef __attribute__((ext_vector_type(4))) float f32x4;

// ---------------- small load/store helpers ----------------
__device__ inline float bfbits2f(unsigned v) { union { unsigned u; float f; } c; c.u = v; return c.f; }

__device__ inline void vload4(const float* p, float o[4]) {
    float4 v = *reinterpret_cast<const float4*>(p);
    o[0] = v.x; o[1] = v.y; o[2] = v.z; o[3] = v.w;
}
__device__ inline void vload4(const __hip_bfloat16* p, float o[4]) {
    uint2 w = *reinterpret_cast<const uint2*>(p);
    o[0] = bfbits2f(w.x << 16); o[1] = bfbits2f(w.x & 0xffff0000u);
    o[2] = bfbits2f(w.y << 16); o[3] = bfbits2f(w.y & 0xffff0000u);
}
__device__ inline float sload(const float* p) { return *p; }
__device__ inline float sload(const __hip_bfloat16* p) { return __bfloat162float(*p); }
__device__ inline void stc(float* p, float v) { *p = v; }
__device__ inline void stc(__hip_bfloat16* p, float v) { *p = __float2bfloat16(v); }

// ---------------- MFMA bf16 GEMM: C = A[M][K] * Bt[N][K]^T (+bias)(+res)(gelu) ----------------
// 128x128 tile, BK=64, 4 waves (2x2), 16x16x32 MFMA, global_load_lds width-16 staging.
// A rows may be read up to next multiple of 128 (caller pads buffers); stores masked by M.
template<int EPI, bool OUTBF>   // EPI: 0 none, 1 +residual, 2 gelu
__global__ __launch_bounds__(256) void gemm_mfma(
    const __hip_bfloat16* __restrict__ A, int lda,
    const __hip_bfloat16* __restrict__ Bt,            // [N][K], ldb=K
    void* __restrict__ Cout, int ldc,
    const float* __restrict__ bias,
    const float* __restrict__ Rm, int ldr,
    int M, int N, int K)
{
    __shared__ __hip_bfloat16 As[128 * 64];
    __shared__ __hip_bfloat16 Bs[128 * 64];

    const int t = threadIdx.x;
    const int wid = t >> 6, lane = t & 63;
    const int wm = wid >> 1, wn = wid & 1;
    const int m0 = blockIdx.y * 128, n0 = blockIdx.x * 128;

    const int srow = t >> 3;            // 0..31 row within 32-row group
    const int scol = (t & 7) * 8;       // 0..56 col (elements)

    f32x4 acc[4][4] = {};

    for (int k0 = 0; k0 < K; k0 += 64) {
        #pragma unroll
        for (int i = 0; i < 4; ++i) {
            const __hip_bfloat16* ga = A + (long)(m0 + i * 32 + srow) * lda + k0 + scol;
            __hip_bfloat16* la = As + (i * 256 + wid * 64) * 8;
            __builtin_amdgcn_global_load_lds(
                (const __attribute__((address_space(1))) void*)ga,
                (__attribute__((address_space(3))) void*)la, 16, 0, 0);
            const __hip_bfloat16* gb = Bt + (long)(n0 + i * 32 + srow) * K + k0 + scol;
            __hip_bfloat16* lb = Bs + (i * 256 + wid * 64) * 8;
            __builtin_amdgcn_global_load_lds(
                (const __attribute__((address_space(1))) void*)gb,
                (__attribute__((address_space(3))) void*)lb, 16, 0, 0);
        }
        asm volatile("s_waitcnt vmcnt(0)" ::: "memory");
        __syncthreads();

        #pragma unroll
        for (int kk = 0; kk < 2; ++kk) {
            bf16x8 af[4], bfr[4];
            #pragma unroll
            for (int mi = 0; mi < 4; ++mi)
                af[mi] = *reinterpret_cast<const bf16x8*>(
                    &As[(wm * 64 + mi * 16 + (lane & 15)) * 64 + kk * 32 + (lane >> 4) * 8]);
            #pragma unroll
            for (int ni = 0; ni < 4; ++ni)
                bfr[ni] = *reinterpret_cast<const bf16x8*>(
                    &Bs[(wn * 64 + ni * 16 + (lane & 15)) * 64 + kk * 32 + (lane >> 4) * 8]);
            #pragma unroll
            for (int mi = 0; mi < 4; ++mi)
                #pragma unroll
                for (int ni = 0; ni < 4; ++ni)
                    acc[mi][ni] = __builtin_amdgcn_mfma_f32_16x16x32_bf16(
                        af[mi], bfr[ni], acc[mi][ni], 0, 0, 0);
        }
        __syncthreads();
    }

    // epilogue: C/D layout col=lane&15, row=(lane>>4)*4+r
    #pragma unroll
    for (int mi = 0; mi < 4; ++mi) {
        #pragma unroll
        for (int r = 0; r < 4; ++r) {
            int gm = m0 + wm * 64 + mi * 16 + (lane >> 4) * 4 + r;
            if (gm >= M) continue;
            #pragma unroll
            for (int ni = 0; ni < 4; ++ni) {
                int gn = n0 + wn * 64 + ni * 16 + (lane & 15);
                float v = acc[mi][ni][r];
                if (bias) v += bias[gn];
                if (EPI == 1) v += Rm[(long)gm * ldr + gn];
                if (EPI == 2) v = 0.5f * v * (1.0f + erff(v * 0.70710678118654752f));
                if (OUTBF) ((__hip_bfloat16*)Cout)[(long)gm * ldc + gn] = __float2bfloat16(v);
                else       ((float*)Cout)[(long)gm * ldc + gn] = v;
            }
        }
    }
}

// ---------------- generic tiled fp32-accum GEMM (small attention matmuls) ----------------
template<typename TA, typename TB, typename TC, bool TRANS_B>
__global__ __launch_bounds__(256) void gemm_tile(
    const TA* __restrict__ A, int lda, long sAhi, long sAlo,
    const TB* __restrict__ Bm, int ldb, long sBhi, long sBlo,
    TC* __restrict__ Cm, int ldc, long sChi, long sClo,
    const float* __restrict__ bias, long sbhi, long sblo,
    int M, int N, int K, int innerB, float alpha)
{
    int z = blockIdx.z;
    int zhi = z / innerB, zlo = z - zhi * innerB;
    A  += zhi * sAhi + zlo * sAlo;
    Bm += zhi * sBhi + zlo * sBlo;
    Cm += zhi * sChi + zlo * sClo;
    if (bias) bias += zhi * sbhi + zlo * sblo;

    __shared__ float As[16][64];
    __shared__ float Bs[16][64];

    const int m0 = blockIdx.y * 64, n0 = blockIdx.x * 64;
    const int t = threadIdx.x;
    const int tm = (t & 15) * 4;
    const int tn = (t >> 4) * 4;

    constexpr uintptr_t AMSK = (sizeof(TA) == 4) ? 15 : 7;
    constexpr uintptr_t BMSK = (sizeof(TB) == 4) ? 15 : 7;
    const bool a4 = ((((uintptr_t)A)  & AMSK) == 0) && ((lda & 3) == 0);
    const bool b4 = ((((uintptr_t)Bm) & BMSK) == 0) && ((ldb & 3) == 0);

    float acc[4][4] = {};

    for (int k0 = 0; k0 < K; k0 += 16) {
        {   // A tile -> As[k][m]
            int r  = t >> 2;
            int kq = (t & 3) * 4;
            int gm = m0 + r;
            float av[4] = {0.f, 0.f, 0.f, 0.f};
            if (gm < M) {
                int kb = k0 + kq;
                if (a4 && (kb + 3 < K)) vload4(&A[(long)gm * lda + kb], av);
                else for (int u = 0; u < 4; ++u) if (kb + u < K) av[u] = sload(&A[(long)gm * lda + kb + u]);
            }
            As[kq + 0][r] = av[0]; As[kq + 1][r] = av[1];
            As[kq + 2][r] = av[2]; As[kq + 3][r] = av[3];
        }
        if (TRANS_B) {
            int r  = t >> 2;
            int kq = (t & 3) * 4;
            int gn = n0 + r;
            float bv[4] = {0.f, 0.f, 0.f, 0.f};
            if (gn < N) {
                int kb = k0 + kq;
                if (b4 && (kb + 3 < K)) vload4(&Bm[(long)gn * ldb + kb], bv);
                else for (int u = 0; u < 4; ++u) if (kb + u < K) bv[u] = sload(&Bm[(long)gn * ldb + kb + u]);
            }
            Bs[kq + 0][r] = bv[0]; Bs[kq + 1][r] = bv[1];
            Bs[kq + 2][r] = bv[2]; Bs[kq + 3][r] = bv[3];
        } else {
            int kr = t >> 4;
            int nq = (t & 15) * 4;
            int gk = k0 + kr;
            float bv[4] = {0.f, 0.f, 0.f, 0.f};
            if (gk < K) {
                int nb = n0 + nq;
                if (b4 && (nb + 3 < N)) vload4(&Bm[(long)gk * ldb + nb], bv);
                else for (int u = 0; u < 4; ++u) if (nb + u < N) bv[u] = sload(&Bm[(long)gk * ldb + nb + u]);
            }
            Bs[kr][nq + 0] = bv[0]; Bs[kr][nq + 1] = bv[1];
            Bs[kr][nq + 2] = bv[2]; Bs[kr][nq + 3] = bv[3];
        }
        __syncthreads();
        #pragma unroll
        for (int kk = 0; kk < 16; ++kk) {
            float4 a = *reinterpret_cast<const float4*>(&As[kk][tm]);
            float4 b = *reinterpret_cast<const float4*>(&Bs[kk][tn]);
            float ar[4] = {a.x, a.y, a.z, a.w};
            float br[4] = {b.x, b.y, b.z, b.w};
            #pragma unroll
            for (int i = 0; i < 4; ++i)
                #pragma unroll
                for (int j = 0; j < 4; ++j)
                    acc[i][j] += ar[i] * br[j];
        }
        __syncthreads();
    }

    for (int i = 0; i < 4; ++i) {
        int gm = m0 + tm + i;
        if (gm >= M) continue;
        for (int j = 0; j < 4; ++j) {
            int gn = n0 + tn + j;
            if (gn >= N) continue;
            float v = acc[i][j] * alpha;
            if (bias) v += bias[gn];
            stc(&Cm[(long)gm * ldc + gn], v);
        }
    }
}

// ---------------- LayerNorm: fp32 in, bf16 out ----------------
__global__ __launch_bounds__(256) void ln_kernel(
    const float* __restrict__ X, const float* __restrict__ g,
    const float* __restrict__ b, __hip_bfloat16* __restrict__ H)
{
    const long row = blockIdx.x;
    const float* x = X + row * DD;
    const int t = threadIdx.x;
    float v[3];
    float s = 0.f, s2 = 0.f;
    #pragma unroll
    for (int i = 0; i < 3; ++i) {
        v[i] = x[t + i * 256];
        s += v[i]; s2 += v[i] * v[i];
    }
    #pragma unroll
    for (int off = 1; off < 64; off <<= 1) {
        s  += __shfl_xor(s,  off);
        s2 += __shfl_xor(s2, off);
    }
    __shared__ float red[2][4];
    const int lane = t & 63, w = t >> 6;
    if (lane == 0) { red[0][w] = s; red[1][w] = s2; }
    __syncthreads();
    float S1 = red[0][0] + red[0][1] + red[0][2] + red[0][3];
    float S2 = red[1][0] + red[1][1] + red[1][2] + red[1][3];
    float mu  = S1 * (1.0f / 768.0f);
    float var = S2 * (1.0f / 768.0f) - mu * mu;
    float rs  = rsqrtf(var + 1e-5f);
    __hip_bfloat16* h = H + row * DD;
    #pragma unroll
    for (int i = 0; i < 3; ++i) {
        int c = t + i * 256;
        h[c] = __float2bfloat16((v[i] - mu) * rs * g[c] + b[c]);
    }
}

// ---------------- softmax over last dim (row length 197) ----------------
__global__ __launch_bounds__(64) void softmax_kernel(float* __restrict__ Sc)
{
    float* p = Sc + (long)blockIdx.x * SS;
    const int t = threadIdx.x;
    float vals[4];
    float mx = -1e30f;
    #pragma unroll
    for (int i = 0; i < 4; ++i) {
        int c = t + i * 64;
        vals[i] = (c < SS) ? p[c] : -1e30f;
        mx = fmaxf(mx, vals[i]);
    }
    #pragma unroll
    for (int off = 1; off < 64; off <<= 1) mx = fmaxf(mx, __shfl_xor(mx, off));
    float sum = 0.f;
    #pragma unroll
    for (int i = 0; i < 4; ++i) {
        int c = t + i * 64;
        if (c < SS) { vals[i] = expf(vals[i] - mx); sum += vals[i]; }
    }
    #pragma unroll
    for (int off = 1; off < 64; off <<= 1) sum += __shfl_xor(sum, off);
    float inv = 1.0f / sum;
    #pragma unroll
    for (int i = 0; i < 4; ++i) {
        int c = t + i * 64;
        if (c < SS) p[c] = vals[i] * inv;
    }
}

// ---------------- patchify: [B,C,H,W] f32 -> [B*196, 768] bf16 ----------------
__global__ void patchify_kernel(const float* __restrict__ img, __hip_bfloat16* __restrict__ patches)
{
    long idx = (long)blockIdx.x * 256 + threadIdx.x;
    const long total = (long)NB * NPAT * DD;
    if (idx >= total) return;
    int k  = (int)(idx % DD);
    long mp = idx / DD;
    int p  = (int)(mp % NPAT);
    long b = mp / NPAT;
    int c = k >> 8;
    int i = (k >> 4) & 15;
    int j = k & 15;
    int pr = p / 14, pc = p % 14;
    int hh = pr * 16 + i, ww = pc * 16 + j;
    patches[idx] = __float2bfloat16(img[((b * 3 + c) * 224 + hh) * 224 + ww]);
}

// ---------------- assemble x = concat(cls, tokens) + pos (fp32) ----------------
__global__ void assemble_kernel(const float* __restrict__ tok, const float* __restrict__ cls,
                                const float* __restrict__ pos, float* __restrict__ X)
{
    long idx = (long)blockIdx.x * 256 + threadIdx.x;
    if (idx >= NX) return;
    int d  = (int)(idx % DD);
    long bs = idx / DD;
    int s  = (int)(bs % SS);
    long b = bs / SS;
    float v = (s == 0) ? cls[d] : tok[(b * NPAT + s - 1) * DD + d];
    X[idx] = v + pos[(long)s * DD + d];
}

__global__ void copy_kernel(const float* __restrict__ src, float* __restrict__ dst, long n)
{
    long i = (long)blockIdx.x * 256 + threadIdx.x;
    if (i < n) dst[i] = src[i];
}

// ---------------- fp32 -> bf16 conversion (n multiple of 4) ----------------
__global__ void f2b_kernel(const float* __restrict__ src, __hip_bfloat16* __restrict__ dst, long n4)
{
    long i = (long)blockIdx.x * 256 + threadIdx.x;
    if (i >= n4) return;
    float4 v = *reinterpret_cast<const float4*>(&src[i * 4]);
    __hip_bfloat16 o[4] = { __float2bfloat16(v.x), __float2bfloat16(v.y),
                            __float2bfloat16(v.z), __float2bfloat16(v.w) };
    *reinterpret_cast<uint2*>(&dst[i * 4]) = *reinterpret_cast<const uint2*>(o);
}

// ---------------- host ----------------
extern "C" void kernel_launch(void* const* d_in, const int* in_sizes, int n_in,
                              void* d_out, int out_size, void* d_ws, size_t ws_size,
                              hipStream_t stream)
{
    const float* images   = (const float*)d_in[0];
    const float* mapper_w = (const float*)d_in[1];
    const float* mapper_b = (const float*)d_in[2];
    const float* cls      = (const float*)d_in[3];
    const float* pos      = (const float*)d_in[4];
    const float* ln1_g    = (const float*)d_in[5];
    const float* ln1_b    = (const float*)d_in[6];
    const float* qw       = (const float*)d_in[7];
    const float* qb       = (const float*)d_in[8];
    const float* kw       = (const float*)d_in[9];
    const float* kb       = (const float*)d_in[10];
    const float* vw       = (const float*)d_in[11];
    const float* vb       = (const float*)d_in[12];
    const float* ow       = (const float*)d_in[13];
    const float* ob       = (const float*)d_in[14];
    const float* ln2_g    = (const float*)d_in[15];
    const float* ln2_b    = (const float*)d_in[16];
    const float* w1       = (const float*)d_in[17];
    const float* b1       = (const float*)d_in[18];
    const float* w2       = (const float*)d_in[19];
    const float* b2       = (const float*)d_in[20];
    float* out = (float*)d_out;

    // ---- workspace layout (bump allocator, 256B aligned)
    char* p0 = (char*)d_ws;
    char* pp = p0;
    auto alloc = [&](size_t bytes) { char* r = pp; pp += (bytes + 255) & ~(size_t)255; return r; };

    float*           x      = (float*)          alloc(NX * 4);
    float*           q      = (float*)          alloc(NX * 4);
    float*           kbuf   = (float*)          alloc(NX * 4);
    float*           v      = (float*)          alloc(NX * 4);
    __hip_bfloat16*  h16    = (__hip_bfloat16*) alloc((size_t)PADM * DD * 2);
    __hip_bfloat16*  ctx16  = (__hip_bfloat16*) alloc((size_t)PADM * DD * 2);
    __hip_bfloat16*  mw16   = (__hip_bfloat16*) alloc((size_t)DD * DD * 2);
    __hip_bfloat16*  wbuf16 = (__hip_bfloat16*) alloc((size_t)(DD*DD + (size_t)FFF*DD*2) * 2);
    const size_t BIGB = (size_t)NB * NHH * SS * SS * 4;  // scores fp32 (largest user)
    char*            big    = alloc(BIGB);

    if ((size_t)(pp - p0) > ws_size) return;

    __hip_bfloat16* patches16 = (__hip_bfloat16*)big;                       // 12544*768 bf16
    float*          tokens    = (float*)(big + ((size_t)12544 * DD * 2 + 255 & ~(size_t)255));
    float*          scores    = (float*)big;
    __hip_bfloat16* mid16     = (__hip_bfloat16*)big;                       // PADM*3072 bf16

    __hip_bfloat16* ow16 = wbuf16;
    __hip_bfloat16* w116 = wbuf16 + (size_t)DD * DD;
    __hip_bfloat16* w216 = w116 + (size_t)FFF * DD;

    // ---- setup: patchify + mapper (MFMA) + assemble
    {
        long n = (long)NB * NPAT * DD;
        patchify_kernel<<<dim3((n + 255) / 256), dim3(256), 0, stream>>>(images, patches16);
        f2b_kernel<<<dim3((DD * DD / 4 + 255) / 256), dim3(256), 0, stream>>>(mapper_w, mw16, DD * DD / 4);
        gemm_mfma<0, false><<<dim3(DD / 128, (NB * NPAT) / 128), dim3(256), 0, stream>>>(
            patches16, DD, mw16, tokens, DD, mapper_b, nullptr, 0, NB * NPAT, DD, DD);
        assemble_kernel<<<dim3((NX + 255) / 256), dim3(256), 0, stream>>>(tokens, cls, pos, x);
    }

    const long sQhi = (long)SS * DD;       // per-image stride in q/k/v/ctx
    const long sShi = (long)NHH * SS * SS; // per-image stride in scores
    const long sSlo = (long)SS * SS;
    const int  MT   = (TOK + 127) / 128;   // 99

    for (int l = 0; l < 12; ++l) {
        // weight conversions for this layer
        f2b_kernel<<<dim3((DD * DD / 4 + 255) / 256), dim3(256), 0, stream>>>(
            ow + (long)l * DD * DD, ow16, DD * DD / 4);
        f2b_kernel<<<dim3((FFF * DD / 4 + 255) / 256), dim3(256), 0, stream>>>(
            w1 + (long)l * FFF * DD, w116, FFF * DD / 4);
        f2b_kernel<<<dim3((FFF * DD / 4 + 255) / 256), dim3(256), 0, stream>>>(
            w2 + (long)l * FFF * DD, w216, FFF * DD / 4);

        // LN1 -> h16
        ln_kernel<<<dim3(TOK), dim3(256), 0, stream>>>(x, ln1_g + l * DD, ln1_b + l * DD, h16);

        // QKV per-head (fp32 accum, bf16 A): M=TOK, N=64, K=64, batch=12 heads
        const float* wv3[3] = { qw + (long)l * NHH * DHH * DHH,
                                kw + (long)l * NHH * DHH * DHH,
                                vw + (long)l * NHH * DHH * DHH };
        const float* bv3[3] = { qb + l * DD, kb + l * DD, vb + l * DD };
        float* ov3[3] = { q, kbuf, v };
        for (int c = 0; c < 3; ++c) {
            gemm_tile<__hip_bfloat16, float, float, true><<<dim3(1, TOK / 64, NHH), dim3(256), 0, stream>>>(
                h16, DD, 0, DHH,
                wv3[c], DHH, 0, (long)DHH * DHH,
                ov3[c], DD, 0, DHH,
                bv3[c], 0, DHH,
                TOK, DHH, DHH, NHH, 1.0f);
        }

        // scores = q k^T / 4096
        gemm_tile<float, float, float, true><<<dim3(4, 4, NB * NHH), dim3(256), 0, stream>>>(
            q, DD, sQhi, DHH,
            kbuf, DD, sQhi, DHH,
            scores, SS, sShi, sSlo,
            nullptr, 0, 0,
            SS, SS, DHH, NHH, 1.0f / 4096.0f);

        softmax_kernel<<<dim3(NB * NHH * SS), dim3(64), 0, stream>>>(scores);

        // ctx16 = attn @ v  (bf16 out)
        gemm_tile<float, float, __hip_bfloat16, false><<<dim3(1, 4, NB * NHH), dim3(256), 0, stream>>>(
            scores, SS, sShi, sSlo,
            v, DD, sQhi, DHH,
            ctx16, DD, sQhi, DHH,
            nullptr, 0, 0,
            SS, DHH, SS, NHH, 1.0f);

        // x = x + ctx @ ow^T + ob   (MFMA)
        gemm_mfma<1, false><<<dim3(DD / 128, MT), dim3(256), 0, stream>>>(
            ctx16, DD, ow16, x, DD, ob + l * DD, x, DD, TOK, DD, DD);

        // LN2 -> h16
        ln_kernel<<<dim3(TOK), dim3(256), 0, stream>>>(x, ln2_g + l * DD, ln2_b + l * DD, h16);

        // mid16 = gelu(h @ w1^T + b1)   (MFMA, bf16 out)
        gemm_mfma<2, true><<<dim3(FFF / 128, MT), dim3(256), 0, stream>>>(
            h16, DD, w116, mid16, FFF, b1 + l * FFF, nullptr, 0, TOK, FFF, DD);

        // x = x + mid @ w2^T + b2   (MFMA)
        gemm_mfma<1, false><<<dim3(DD / 128, MT), dim3(256), 0, stream>>>(
            mid16, FFF, w216, x, DD, b2 + l * DD, x, DD, TOK, DD, FFF);

        // extract
        int slot = (l == 2) ? 0 : (l == 5) ? 1 : (l == 8) ? 2 : (l == 11) ? 3 : -1;
        if (slot >= 0) {
            copy_kernel<<<dim3((NX + 255) / 256), dim3(256), 0, stream>>>(
                x, out + (long)slot * NX, NX);
        }
    }
}

// Round 3
// 9139.813 us; speedup vs baseline: 3.2137x; 1.2359x over previous
//
#include <hip/hip_runtime.h>
#include <hip/hip_bf16.h>
#include <math.h>

// ---------------- problem constants ----------------
static constexpr int NB   = 64;           // batch
static constexpr int SS   = 197;          // tokens
static constexpr int DD   = 768;          // hidden
static constexpr int NHH  = 12;           // heads
static constexpr int DHH  = 64;           // head dim
static constexpr int FFF  = 3072;         // mlp hidden
static constexpr int TOK  = NB * SS;      // 12608
static constexpr int NPAT = 196;          // patches per image
static constexpr int PADM = 12672;        // TOK padded to multiple of 128
static constexpr long NX  = (long)TOK * DD;  // 9,682,944
static constexpr int SLD  = 208;          // scores row pitch (bf16, 16B aligned)
static constexpr int APAD = 256;          // attn row pitch (K-padded, zero-filled)

typedef __attribute__((ext_vector_type(8))) short bf16x8;
typedef __attribute__((ext_vector_type(4))) float f32x4;

// ---------------- MFMA bf16 GEMM ----------------
// C = alpha * A[M][K] * Bt[N][K]^T  (+bias[n]) (epilogues below)
// 128x128 tile, BK=64, 4 waves (2x2), 16x16x32 MFMA, global_load_lds width-16.
// Batched: z -> (zhi = z/innerB, zlo = z%innerB); offsets via (hi,lo) strides.
// A/Bt rows may be over-read up to tile bounds (caller pads buffers); stores masked.
// EPI: 0 none, 1 +residual (optional dup-store to out2), 2 gelu, 3 qkv-scatter
template<int EPI, bool OUTBF>
__global__ __launch_bounds__(256) void gemm_mfma(
    const __hip_bfloat16* __restrict__ A, int lda, long sAhi, long sAlo,
    const __hip_bfloat16* __restrict__ Bt, int ldb, long sBhi, long sBlo,
    void* __restrict__ Cout, int ldc, long sChi, long sClo,
    const float* __restrict__ bias, long sbhi, long sblo,
    const float* __restrict__ Rm, int ldr,
    float* __restrict__ out2,
    __hip_bfloat16* __restrict__ qb_, __hip_bfloat16* __restrict__ kb_,
    __hip_bfloat16* __restrict__ vtb,
    int M, int N, int K, int innerB, float alpha)
{
    __shared__ __hip_bfloat16 As[128 * 64];
    __shared__ __hip_bfloat16 Bs[128 * 64];

    const int zz  = blockIdx.z;
    const int zhi = zz / innerB, zlo = zz - zhi * innerB;
    A  += zhi * sAhi + zlo * sAlo;
    Bt += zhi * sBhi + zlo * sBlo;
    char* Cb = (char*)Cout;
    if (Cout) Cb += (zhi * sChi + zlo * sClo) * (OUTBF ? 2 : 4);
    if (bias) bias += zhi * sbhi + zlo * sblo;

    const int t = threadIdx.x;
    const int wid = t >> 6, lane = t & 63;
    const int wm = wid >> 1, wn = wid & 1;
    const int m0 = blockIdx.y * 128, n0 = blockIdx.x * 128;

    const int srow = t >> 3;            // 0..31 row within 32-row group
    const int scol = (t & 7) * 8;       // element col

    f32x4 acc[4][4] = {};

    for (int k0 = 0; k0 < K; k0 += 64) {
        #pragma unroll
        for (int i = 0; i < 4; ++i) {
            const __hip_bfloat16* ga = A + (long)(m0 + i * 32 + srow) * lda + k0 + scol;
            __hip_bfloat16* la = As + (i * 256 + wid * 64) * 8;
            __builtin_amdgcn_global_load_lds(
                (const __attribute__((address_space(1))) void*)ga,
                (__attribute__((address_space(3))) void*)la, 16, 0, 0);
            const __hip_bfloat16* gb = Bt + (long)(n0 + i * 32 + srow) * ldb + k0 + scol;
            __hip_bfloat16* lb = Bs + (i * 256 + wid * 64) * 8;
            __builtin_amdgcn_global_load_lds(
                (const __attribute__((address_space(1))) void*)gb,
                (__attribute__((address_space(3))) void*)lb, 16, 0, 0);
        }
        asm volatile("s_waitcnt vmcnt(0)" ::: "memory");
        __syncthreads();

        #pragma unroll
        for (int kk = 0; kk < 2; ++kk) {
            bf16x8 af[4], bfr[4];
            #pragma unroll
            for (int mi = 0; mi < 4; ++mi)
                af[mi] = *reinterpret_cast<const bf16x8*>(
                    &As[(wm * 64 + mi * 16 + (lane & 15)) * 64 + kk * 32 + (lane >> 4) * 8]);
            #pragma unroll
            for (int ni = 0; ni < 4; ++ni)
                bfr[ni] = *reinterpret_cast<const bf16x8*>(
                    &Bs[(wn * 64 + ni * 16 + (lane & 15)) * 64 + kk * 32 + (lane >> 4) * 8]);
            #pragma unroll
            for (int mi = 0; mi < 4; ++mi)
                #pragma unroll
                for (int ni = 0; ni < 4; ++ni)
                    acc[mi][ni] = __builtin_amdgcn_mfma_f32_16x16x32_bf16(
                        af[mi], bfr[ni], acc[mi][ni], 0, 0, 0);
        }
        __syncthreads();
    }

    // epilogue: C/D layout col=lane&15, row=(lane>>4)*4+r
    #pragma unroll
    for (int mi = 0; mi < 4; ++mi) {
        #pragma unroll
        for (int r = 0; r < 4; ++r) {
            int gm = m0 + wm * 64 + mi * 16 + (lane >> 4) * 4 + r;
            if (gm >= M) continue;
            int bq = 0, sq = 0;
            if (EPI == 3) { bq = gm / 197; sq = gm - bq * 197; }
            #pragma unroll
            for (int ni = 0; ni < 4; ++ni) {
                int gn = n0 + wn * 64 + ni * 16 + (lane & 15);
                if (gn >= N) continue;
                float v = acc[mi][ni][r] * alpha;
                if (bias) v += bias[gn];
                if (EPI == 1) v += Rm[(long)gm * ldr + gn];
                if (EPI == 2) v = 0.5f * v * (1.0f + erff(v * 0.70710678118654752f));
                if (EPI == 3) {
                    int c = gn >> 6, e = gn & 63;
                    __hip_bfloat16 bv = __float2bfloat16(v);
                    if (c == 0)      qb_[(long)gm * DD + zz * 64 + e] = bv;
                    else if (c == 1) kb_[(long)gm * DD + zz * 64 + e] = bv;
                    else             vtb[(((long)(bq * NHH + zz)) * 128 + e) * APAD + sq] = bv;
                } else if (OUTBF) {
                    ((__hip_bfloat16*)Cb)[(long)gm * ldc + gn] = __float2bfloat16(v);
                } else {
                    ((float*)Cb)[(long)gm * ldc + gn] = v;
                    if (EPI == 1 && out2) out2[(long)gm * ldc + gn] = v;
                }
            }
        }
    }
}

// ---------------- LayerNorm: fp32 in, bf16 out ----------------
__global__ __launch_bounds__(256) void ln_kernel(
    const float* __restrict__ X, const float* __restrict__ g,
    const float* __restrict__ b, __hip_bfloat16* __restrict__ H)
{
    const long row = blockIdx.x;
    const float* x = X + row * DD;
    const int t = threadIdx.x;
    float v[3];
    float s = 0.f, s2 = 0.f;
    #pragma unroll
    for (int i = 0; i < 3; ++i) {
        v[i] = x[t + i * 256];
        s += v[i]; s2 += v[i] * v[i];
    }
    #pragma unroll
    for (int off = 1; off < 64; off <<= 1) {
        s  += __shfl_xor(s,  off);
        s2 += __shfl_xor(s2, off);
    }
    __shared__ float red[2][4];
    const int lane = t & 63, w = t >> 6;
    if (lane == 0) { red[0][w] = s; red[1][w] = s2; }
    __syncthreads();
    float S1 = red[0][0] + red[0][1] + red[0][2] + red[0][3];
    float S2 = red[1][0] + red[1][1] + red[1][2] + red[1][3];
    float mu  = S1 * (1.0f / 768.0f);
    float var = S2 * (1.0f / 768.0f) - mu * mu;
    float rs  = rsqrtf(var + 1e-5f);
    __hip_bfloat16* h = H + row * DD;
    #pragma unroll
    for (int i = 0; i < 3; ++i) {
        int c = t + i * 256;
        h[c] = __float2bfloat16((v[i] - mu) * rs * g[c] + b[c]);
    }
}

// ---------------- softmax: scores bf16[ld=SLD] -> attn bf16[ld=APAD], zero-padded ----------------
__global__ __launch_bounds__(256) void softmax_kernel(
    const __hip_bfloat16* __restrict__ Sc, __hip_bfloat16* __restrict__ At, int nrows)
{
    int row = blockIdx.x * 4 + (threadIdx.x >> 6);
    if (row >= nrows) return;
    const __hip_bfloat16* p = Sc + (long)row * SLD;
    __hip_bfloat16* o = At + (long)row * APAD;
    const int t = threadIdx.x & 63;
    float vals[4];
    float mx = -1e30f;
    #pragma unroll
    for (int i = 0; i < 4; ++i) {
        int c = t + i * 64;
        vals[i] = (c < SS) ? __bfloat162float(p[c]) : -1e30f;
        mx = fmaxf(mx, vals[i]);
    }
    #pragma unroll
    for (int off = 1; off < 64; off <<= 1) mx = fmaxf(mx, __shfl_xor(mx, off));
    float sum = 0.f;
    #pragma unroll
    for (int i = 0; i < 4; ++i) {
        vals[i] = expf(vals[i] - mx);
        sum += vals[i];
    }
    #pragma unroll
    for (int off = 1; off < 64; off <<= 1) sum += __shfl_xor(sum, off);
    float inv = 1.0f / sum;
    #pragma unroll
    for (int i = 0; i < 4; ++i) {
        int c = t + i * 64;
        o[c] = __float2bfloat16((c < SS) ? vals[i] * inv : 0.0f);
    }
}

// ---------------- patchify: [B,C,H,W] f32 -> [B*196, 768] bf16 ----------------
__global__ void patchify_kernel(const float* __restrict__ img, __hip_bfloat16* __restrict__ patches)
{
    long idx = (long)blockIdx.x * 256 + threadIdx.x;
    const long total = (long)NB * NPAT * DD;
    if (idx >= total) return;
    int k  = (int)(idx % DD);
    long mp = idx / DD;
    int p  = (int)(mp % NPAT);
    long b = mp / NPAT;
    int c = k >> 8;
    int i = (k >> 4) & 15;
    int j = k & 15;
    int pr = p / 14, pc = p % 14;
    int hh = pr * 16 + i, ww = pc * 16 + j;
    patches[idx] = __float2bfloat16(img[((b * 3 + c) * 224 + hh) * 224 + ww]);
}

// ---------------- assemble x = concat(cls, tokens) + pos (fp32) ----------------
__global__ void assemble_kernel(const float* __restrict__ tok, const float* __restrict__ cls,
                                const float* __restrict__ pos, float* __restrict__ X)
{
    long idx = (long)blockIdx.x * 256 + threadIdx.x;
    if (idx >= NX) return;
    int d  = (int)(idx % DD);
    long bs = idx / DD;
    int s  = (int)(bs % SS);
    long b = bs / SS;
    float v = (s == 0) ? cls[d] : tok[(b * NPAT + s - 1) * DD + d];
    X[idx] = v + pos[(long)s * DD + d];
}

// ---------------- fp32 -> bf16 conversion (n multiple of 4) ----------------
__global__ void f2b_kernel(const float* __restrict__ src, __hip_bfloat16* __restrict__ dst, long n4)
{
    long i = (long)blockIdx.x * 256 + threadIdx.x;
    if (i >= n4) return;
    float4 v = *reinterpret_cast<const float4*>(&src[i * 4]);
    __hip_bfloat16 o[4] = { __float2bfloat16(v.x), __float2bfloat16(v.y),
                            __float2bfloat16(v.z), __float2bfloat16(v.w) };
    *reinterpret_cast<uint2*>(&dst[i * 4]) = *reinterpret_cast<const uint2*>(o);
}

// ---------------- pack per-head qkv weights: wqkv[12][256][64] rows 0..191, bqkv[12][192] ----------------
__global__ void qkvpack_kernel(const float* __restrict__ qw, const float* __restrict__ kw,
                               const float* __restrict__ vw, const float* __restrict__ qb,
                               const float* __restrict__ kb, const float* __restrict__ vb,
                               __hip_bfloat16* __restrict__ W, float* __restrict__ Bv)
{
    int idx = blockIdx.x * 256 + threadIdx.x;   // over 12*192*64
    if (idx >= NHH * 192 * 64) return;
    int d = idx & 63;
    int rest = idx >> 6;
    int j = rest % 192;
    int h = rest / 192;
    int c = j >> 6, e = j & 63;
    const float* src = (c == 0 ? qw : c == 1 ? kw : vw) + ((long)h * 64 + e) * 64 + d;
    W[((long)h * 256 + j) * 64 + d] = __float2bfloat16(*src);
    if (d == 0) {
        const float* sb = (c == 0 ? qb : c == 1 ? kb : vb) + h * 64 + e;
        Bv[h * 192 + j] = *sb;
    }
}

// ---------------- host ----------------
extern "C" void kernel_launch(void* const* d_in, const int* in_sizes, int n_in,
                              void* d_out, int out_size, void* d_ws, size_t ws_size,
                              hipStream_t stream)
{
    const float* images   = (const float*)d_in[0];
    const float* mapper_w = (const float*)d_in[1];
    const float* mapper_b = (const float*)d_in[2];
    const float* cls      = (const float*)d_in[3];
    const float* pos      = (const float*)d_in[4];
    const float* ln1_g    = (const float*)d_in[5];
    const float* ln1_b    = (const float*)d_in[6];
    const float* qw       = (const float*)d_in[7];
    const float* qb       = (const float*)d_in[8];
    const float* kw       = (const float*)d_in[9];
    const float* kb       = (const float*)d_in[10];
    const float* vw       = (const float*)d_in[11];
    const float* vb       = (const float*)d_in[12];
    const float* ow       = (const float*)d_in[13];
    const float* ob       = (const float*)d_in[14];
    const float* ln2_g    = (const float*)d_in[15];
    const float* ln2_b    = (const float*)d_in[16];
    const float* w1       = (const float*)d_in[17];
    const float* b1       = (const float*)d_in[18];
    const float* w2       = (const float*)d_in[19];
    const float* b2       = (const float*)d_in[20];
    float* out = (float*)d_out;

    // ---- workspace (bump allocator, 256B aligned)
    char* p0 = (char*)d_ws;
    char* pp = p0;
    auto alloc = [&](size_t bytes) { char* r = pp; pp += (bytes + 255) & ~(size_t)255; return r; };

    float*           x      = (float*)          alloc(NX * 4);
    __hip_bfloat16*  h16    = (__hip_bfloat16*) alloc((size_t)PADM * DD * 2);
    __hip_bfloat16*  ctx16  = (__hip_bfloat16*) alloc((size_t)PADM * DD * 2);
    __hip_bfloat16*  wbuf16 = (__hip_bfloat16*) alloc((size_t)(DD*DD + (size_t)FFF*DD*2) * 2);
    __hip_bfloat16*  wqkv16 = (__hip_bfloat16*) alloc((size_t)NHH * 256 * 64 * 2);
    float*           bqkv   = (float*)          alloc((size_t)NHH * 192 * 4);
    __hip_bfloat16*  qbuf   = (__hip_bfloat16*) alloc((size_t)PADM * DD * 2);
    __hip_bfloat16*  kbuf   = (__hip_bfloat16*) alloc((size_t)PADM * DD * 2);
    __hip_bfloat16*  vt     = (__hip_bfloat16*) alloc((size_t)NB * NHH * 128 * APAD * 2);
    __hip_bfloat16*  attn   = (__hip_bfloat16*) alloc(((size_t)NB * NHH * SS + 64) * APAD * 2);
    // shared region: scores (62.9MB) | mid16 (77.9MB) | patches+tokens (57.9MB)
    char*            big    = alloc((size_t)PADM * FFF * 2);

    if ((size_t)(pp - p0) > ws_size) return;

    __hip_bfloat16* scores16  = (__hip_bfloat16*)big;
    __hip_bfloat16* mid16     = (__hip_bfloat16*)big;
    __hip_bfloat16* patches16 = (__hip_bfloat16*)big;
    float*          tokens    = (float*)(big + (((size_t)NB * NPAT * DD * 2 + 255) & ~(size_t)255));

    __hip_bfloat16* ow16 = wbuf16;
    __hip_bfloat16* w116 = wbuf16 + (size_t)DD * DD;
    __hip_bfloat16* w216 = w116 + (size_t)FFF * DD;

    // ---- setup: patchify + mapper (MFMA, reuses w116 slot) + assemble
    {
        long n = (long)NB * NPAT * DD;
        patchify_kernel<<<dim3((n + 255) / 256), dim3(256), 0, stream>>>(images, patches16);
        f2b_kernel<<<dim3((DD * DD / 4 + 255) / 256), dim3(256), 0, stream>>>(mapper_w, w116, DD * DD / 4);
        gemm_mfma<0, false><<<dim3(DD / 128, (NB * NPAT) / 128, 1), dim3(256), 0, stream>>>(
            patches16, DD, 0, 0, w116, DD, 0, 0, tokens, DD, 0, 0,
            mapper_b, 0, 0, nullptr, 0, nullptr, nullptr, nullptr, nullptr,
            NB * NPAT, DD, DD, 1, 1.0f);
        assemble_kernel<<<dim3((NX + 255) / 256), dim3(256), 0, stream>>>(tokens, cls, pos, x);
    }

    const int MT = (TOK + 127) / 128;   // 99

    for (int l = 0; l < 12; ++l) {
        // ---- weight prep for this layer
        f2b_kernel<<<dim3((DD * DD / 4 + 255) / 256), dim3(256), 0, stream>>>(
            ow + (long)l * DD * DD, ow16, DD * DD / 4);
        f2b_kernel<<<dim3((FFF * DD / 4 + 255) / 256), dim3(256), 0, stream>>>(
            w1 + (long)l * FFF * DD, w116, FFF * DD / 4);
        f2b_kernel<<<dim3((FFF * DD / 4 + 255) / 256), dim3(256), 0, stream>>>(
            w2 + (long)l * FFF * DD, w216, FFF * DD / 4);
        qkvpack_kernel<<<dim3((NHH * 192 * 64 + 255) / 256), dim3(256), 0, stream>>>(
            qw + (long)l * NHH * DHH * DHH, kw + (long)l * NHH * DHH * DHH,
            vw + (long)l * NHH * DHH * DHH,
            qb + (long)l * DD, kb + (long)l * DD, vb + (long)l * DD,
            wqkv16, bqkv);

        // ---- LN1 -> h16
        ln_kernel<<<dim3(TOK), dim3(256), 0, stream>>>(x, ln1_g + l * DD, ln1_b + l * DD, h16);

        // ---- QKV: batched per head, scatter epilogue (q,k row-major; v transposed)
        gemm_mfma<3, true><<<dim3(2, MT, NHH), dim3(256), 0, stream>>>(
            h16, DD, 64, 0,
            wqkv16, 64, (long)256 * 64, 0,
            nullptr, 0, 0, 0,
            bqkv, 192, 0,
            nullptr, 0, nullptr,
            qbuf, kbuf, vt,
            TOK, 192, 64, 1, 1.0f);

        // ---- scores = q k^T / 4096  (z = b*12+h)
        gemm_mfma<0, true><<<dim3(2, 2, NB * NHH), dim3(256), 0, stream>>>(
            qbuf, DD, (long)SS * DD, 64,
            kbuf, DD, (long)SS * DD, 64,
            scores16, SLD, (long)NHH * SS * SLD, (long)SS * SLD,
            nullptr, 0, 0,
            nullptr, 0, nullptr, nullptr, nullptr, nullptr,
            SS, SS, 64, NHH, 1.0f / 4096.0f);

        // ---- softmax -> attn (bf16, zero-padded to APAD)
        {
            int nrows = NB * NHH * SS;
            softmax_kernel<<<dim3((nrows + 3) / 4), dim3(256), 0, stream>>>(scores16, attn, nrows);
        }

        // ---- ctx = attn @ v  (NT with vt; z = b*12+h)
        gemm_mfma<0, true><<<dim3(1, 2, NB * NHH), dim3(256), 0, stream>>>(
            attn, APAD, (long)NHH * SS * APAD, (long)SS * APAD,
            vt, APAD, (long)NHH * 128 * APAD, (long)128 * APAD,
            ctx16, DD, (long)SS * DD, 64,
            nullptr, 0, 0,
            nullptr, 0, nullptr, nullptr, nullptr, nullptr,
            SS, DHH, APAD, NHH, 1.0f);

        // ---- x = x + ctx @ ow^T + ob
        gemm_mfma<1, false><<<dim3(DD / 128, MT, 1), dim3(256), 0, stream>>>(
            ctx16, DD, 0, 0, ow16, DD, 0, 0, x, DD, 0, 0,
            ob + l * DD, 0, 0, x, DD, nullptr, nullptr, nullptr, nullptr,
            TOK, DD, DD, 1, 1.0f);

        // ---- LN2 -> h16
        ln_kernel<<<dim3(TOK), dim3(256), 0, stream>>>(x, ln2_g + l * DD, ln2_b + l * DD, h16);

        // ---- mid = gelu(h @ w1^T + b1)
        gemm_mfma<2, true><<<dim3(FFF / 128, MT, 1), dim3(256), 0, stream>>>(
            h16, DD, 0, 0, w116, DD, 0, 0, mid16, FFF, 0, 0,
            b1 + l * FFF, 0, 0, nullptr, 0, nullptr, nullptr, nullptr, nullptr,
            TOK, FFF, DD, 1, 1.0f);

        // ---- x = x + mid @ w2^T + b2 (+ fused extraction)
        int slot = (l == 2) ? 0 : (l == 5) ? 1 : (l == 8) ? 2 : (l == 11) ? 3 : -1;
        float* o2 = (slot >= 0) ? out + (long)slot * NX : nullptr;
        gemm_mfma<1, false><<<dim3(DD / 128, MT, 1), dim3(256), 0, stream>>>(
            mid16, FFF, 0, 0, w216, FFF, 0, 0, x, DD, 0, 0,
            b2 + l * DD, 0, 0, x, DD, o2, nullptr, nullptr, nullptr,
            TOK, DD, FFF, 1, 1.0f);
    }
}

// Round 4
// 8442.793 us; speedup vs baseline: 3.4790x; 1.0826x over previous
//
#include <hip/hip_runtime.h>
#include <hip/hip_bf16.h>
#include <math.h>

// ---------------- problem constants ----------------
static constexpr int NB   = 64;           // batch
static constexpr int SS   = 197;          // tokens
static constexpr int DD   = 768;          // hidden
static constexpr int NHH  = 12;           // heads
static constexpr int DHH  = 64;           // head dim
static constexpr int FFF  = 3072;         // mlp hidden
static constexpr int TOK  = NB * SS;      // 12608
static constexpr int NPAT = 196;          // patches per image
static constexpr int PADM = 12672;        // TOK padded to multiple of 128
static constexpr int PADM2= 12800;        // TOK padded to multiple of 256
static constexpr long NX  = (long)TOK * DD;  // 9,682,944
static constexpr int SLD  = 208;          // scores row pitch (bf16, 16B aligned)
static constexpr int APAD = 256;          // attn row pitch (K-padded, zero-filled)

typedef __attribute__((ext_vector_type(8))) short bf16x8;
typedef __attribute__((ext_vector_type(4))) float f32x4;

// =====================================================================
// 256x256 tile bf16 MFMA GEMM, BK=32, 8 waves (2Mx4N), 4-deep LDS pipeline
// C = A[M][K] * Bt[N][K]^T (+bias[n]) (+residual) (gelu)
// T2: LDS slot-XOR swizzle; T3/T4: counted vmcnt(4), raw barriers; T5: setprio
// A rows over-read to next multiple of 256 (caller pads); N,K multiples of 256/32.
// EPI: 0 none, 1 +residual (opt dup-store out2), 2 gelu
// =====================================================================
template<int EPI, bool OUTBF>
__global__ __launch_bounds__(512, 2) void gemm_mfma256(
    const __hip_bfloat16* __restrict__ A, int lda,
    const __hip_bfloat16* __restrict__ Bt, int ldb,
    void* __restrict__ Cout, int ldc,
    const float* __restrict__ bias,
    const float* __restrict__ Rm, int ldr,
    float* __restrict__ out2,
    int M, int N, int K)
{
    __shared__ __hip_bfloat16 As[4][256 * 32];   // 64 KiB
    __shared__ __hip_bfloat16 Bs[4][256 * 32];   // 64 KiB

    const int t = threadIdx.x;
    const int wid = t >> 6, lane = t & 63;
    const int wm = wid >> 2, wn = wid & 3;
    const int m0 = blockIdx.y * 256, n0 = blockIdx.x * 256;

    const int srow  = t >> 2;      // 0..127 (staging row within 128-row half)
    const int sslot = t & 3;       // 16B slot within 64B row

    const int NT = K >> 5;

    auto stageA = [&](int w, int k0) {
        #pragma unroll
        for (int j = 0; j < 2; ++j) {
            int row  = j * 128 + srow;
            int gcol = (sslot ^ (row & 3)) << 3;   // inverse-swizzled source col
            const __hip_bfloat16* ga = A + (long)(m0 + row) * lda + k0 + gcol;
            __hip_bfloat16* la = &As[w][row * 32 + sslot * 8];   // linear dest
            __builtin_amdgcn_global_load_lds(
                (const __attribute__((address_space(1))) void*)ga,
                (__attribute__((address_space(3))) void*)la, 16, 0, 0);
        }
    };
    auto stageB = [&](int w, int k0) {
        #pragma unroll
        for (int j = 0; j < 2; ++j) {
            int row  = j * 128 + srow;
            int gcol = (sslot ^ (row & 3)) << 3;
            const __hip_bfloat16* gb = Bt + (long)(n0 + row) * ldb + k0 + gcol;
            __hip_bfloat16* lb = &Bs[w][row * 32 + sslot * 8];
            __builtin_amdgcn_global_load_lds(
                (const __attribute__((address_space(1))) void*)gb,
                (__attribute__((address_space(3))) void*)lb, 16, 0, 0);
        }
    };

    f32x4 acc[8][4] = {};

    // prologue: stage tiles 0 and 1 (NT >= 2 always here)
    stageA(0, 0); stageB(0, 0);
    stageA(1, 32); stageB(1, 32);
    asm volatile("s_waitcnt vmcnt(4)" ::: "memory");   // tile0 landed, tile1 in flight
    __builtin_amdgcn_s_barrier();
    __builtin_amdgcn_sched_barrier(0);

    // fragment addressing (swizzled read side)
    const int arow = wm * 128 + (lane & 15);
    const int brow = wn * 64 + (lane & 15);
    const int asl  = (((lane >> 4) ^ (lane & 3)) << 3);   // effective slot * 8 elems

    for (int tt = 0; tt < NT; ++tt) {
        const int cb = tt & 3;
        const int wb = (tt + 2) & 3;
        const bool more2 = (tt + 2 < NT);
        const bool more1 = (tt + 1 < NT);

        // -------- phase 0: A-frags + B-frags(ni 0,1); stage A(t+2); MFMA half
        bf16x8 af[8], bfr0, bfr1;
        #pragma unroll
        for (int mi = 0; mi < 8; ++mi)
            af[mi] = *reinterpret_cast<const bf16x8*>(&As[cb][(arow + mi * 16) * 32 + asl]);
        bfr0 = *reinterpret_cast<const bf16x8*>(&Bs[cb][(brow + 0) * 32 + asl]);
        bfr1 = *reinterpret_cast<const bf16x8*>(&Bs[cb][(brow + 16) * 32 + asl]);
        if (more2) stageA(wb, (tt + 2) << 5);
        __builtin_amdgcn_s_setprio(1);
        #pragma unroll
        for (int mi = 0; mi < 8; ++mi) {
            acc[mi][0] = __builtin_amdgcn_mfma_f32_16x16x32_bf16(af[mi], bfr0, acc[mi][0], 0, 0, 0);
            acc[mi][1] = __builtin_amdgcn_mfma_f32_16x16x32_bf16(af[mi], bfr1, acc[mi][1], 0, 0, 0);
        }
        __builtin_amdgcn_s_setprio(0);
        __builtin_amdgcn_s_barrier();
        __builtin_amdgcn_sched_barrier(0);

        // -------- phase 1: B-frags(ni 2,3); stage B(t+2); MFMA half; counted wait
        bf16x8 bfr2 = *reinterpret_cast<const bf16x8*>(&Bs[cb][(brow + 32) * 32 + asl]);
        bf16x8 bfr3 = *reinterpret_cast<const bf16x8*>(&Bs[cb][(brow + 48) * 32 + asl]);
        if (more2) stageB(wb, (tt + 2) << 5);
        __builtin_amdgcn_s_setprio(1);
        #pragma unroll
        for (int mi = 0; mi < 8; ++mi) {
            acc[mi][2] = __builtin_amdgcn_mfma_f32_16x16x32_bf16(af[mi], bfr2, acc[mi][2], 0, 0, 0);
            acc[mi][3] = __builtin_amdgcn_mfma_f32_16x16x32_bf16(af[mi], bfr3, acc[mi][3], 0, 0, 0);
        }
        __builtin_amdgcn_s_setprio(0);
        __builtin_amdgcn_sched_barrier(0);
        if (more2)      { asm volatile("s_waitcnt vmcnt(4)" ::: "memory"); }  // t+1 done, t+2 in flight
        else if (more1) { asm volatile("s_waitcnt vmcnt(0)" ::: "memory"); }  // tail drain
        __builtin_amdgcn_s_barrier();
        __builtin_amdgcn_sched_barrier(0);
    }

    // -------- epilogue: C/D layout col=lane&15, row=(lane>>4)*4+r
    #pragma unroll
    for (int mi = 0; mi < 8; ++mi) {
        #pragma unroll
        for (int r = 0; r < 4; ++r) {
            int gm = m0 + wm * 128 + mi * 16 + (lane >> 4) * 4 + r;
            if (gm >= M) continue;
            #pragma unroll
            for (int ni = 0; ni < 4; ++ni) {
                int gn = n0 + wn * 64 + ni * 16 + (lane & 15);
                float v = acc[mi][ni][r];
                if (bias) v += bias[gn];
                if (EPI == 1) v += Rm[(long)gm * ldr + gn];
                if (EPI == 2) v = 0.5f * v * (1.0f + erff(v * 0.70710678118654752f));
                if (OUTBF) {
                    ((__hip_bfloat16*)Cout)[(long)gm * ldc + gn] = __float2bfloat16(v);
                } else {
                    ((float*)Cout)[(long)gm * ldc + gn] = v;
                    if (EPI == 1 && out2) out2[(long)gm * ldc + gn] = v;
                }
            }
        }
    }
}

// =====================================================================
// 128x128 tile MFMA GEMM (attention-sized matmuls), m97 structure, batched
// EPI: 0 none, 3 qkv-scatter
// =====================================================================
template<int EPI, bool OUTBF>
__global__ __launch_bounds__(256) void gemm_mfma(
    const __hip_bfloat16* __restrict__ A, int lda, long sAhi, long sAlo,
    const __hip_bfloat16* __restrict__ Bt, int ldb, long sBhi, long sBlo,
    void* __restrict__ Cout, int ldc, long sChi, long sClo,
    const float* __restrict__ bias, long sbhi, long sblo,
    const float* __restrict__ Rm, int ldr,
    float* __restrict__ out2,
    __hip_bfloat16* __restrict__ qb_, __hip_bfloat16* __restrict__ kb_,
    __hip_bfloat16* __restrict__ vtb,
    int M, int N, int K, int innerB, float alpha)
{
    __shared__ __hip_bfloat16 As[128 * 64];
    __shared__ __hip_bfloat16 Bs[128 * 64];

    const int zz  = blockIdx.z;
    const int zhi = zz / innerB, zlo = zz - zhi * innerB;
    A  += zhi * sAhi + zlo * sAlo;
    Bt += zhi * sBhi + zlo * sBlo;
    char* Cb = (char*)Cout;
    if (Cout) Cb += (zhi * sChi + zlo * sClo) * (OUTBF ? 2 : 4);
    if (bias) bias += zhi * sbhi + zlo * sblo;

    const int t = threadIdx.x;
    const int wid = t >> 6, lane = t & 63;
    const int wm = wid >> 1, wn = wid & 1;
    const int m0 = blockIdx.y * 128, n0 = blockIdx.x * 128;

    const int srow = t >> 3;
    const int scol = (t & 7) * 8;

    f32x4 acc[4][4] = {};

    for (int k0 = 0; k0 < K; k0 += 64) {
        #pragma unroll
        for (int i = 0; i < 4; ++i) {
            const __hip_bfloat16* ga = A + (long)(m0 + i * 32 + srow) * lda + k0 + scol;
            __hip_bfloat16* la = As + (i * 256 + wid * 64) * 8;
            __builtin_amdgcn_global_load_lds(
                (const __attribute__((address_space(1))) void*)ga,
                (__attribute__((address_space(3))) void*)la, 16, 0, 0);
            const __hip_bfloat16* gb = Bt + (long)(n0 + i * 32 + srow) * ldb + k0 + scol;
            __hip_bfloat16* lb = Bs + (i * 256 + wid * 64) * 8;
            __builtin_amdgcn_global_load_lds(
                (const __attribute__((address_space(1))) void*)gb,
                (__attribute__((address_space(3))) void*)lb, 16, 0, 0);
        }
        asm volatile("s_waitcnt vmcnt(0)" ::: "memory");
        __syncthreads();

        #pragma unroll
        for (int kk = 0; kk < 2; ++kk) {
            bf16x8 af[4], bfr[4];
            #pragma unroll
            for (int mi = 0; mi < 4; ++mi)
                af[mi] = *reinterpret_cast<const bf16x8*>(
                    &As[(wm * 64 + mi * 16 + (lane & 15)) * 64 + kk * 32 + (lane >> 4) * 8]);
            #pragma unroll
            for (int ni = 0; ni < 4; ++ni)
                bfr[ni] = *reinterpret_cast<const bf16x8*>(
                    &Bs[(wn * 64 + ni * 16 + (lane & 15)) * 64 + kk * 32 + (lane >> 4) * 8]);
            #pragma unroll
            for (int mi = 0; mi < 4; ++mi)
                #pragma unroll
                for (int ni = 0; ni < 4; ++ni)
                    acc[mi][ni] = __builtin_amdgcn_mfma_f32_16x16x32_bf16(
                        af[mi], bfr[ni], acc[mi][ni], 0, 0, 0);
        }
        __syncthreads();
    }

    #pragma unroll
    for (int mi = 0; mi < 4; ++mi) {
        #pragma unroll
        for (int r = 0; r < 4; ++r) {
            int gm = m0 + wm * 64 + mi * 16 + (lane >> 4) * 4 + r;
            if (gm >= M) continue;
            int bq = 0, sq = 0;
            if (EPI == 3) { bq = gm / 197; sq = gm - bq * 197; }
            #pragma unroll
            for (int ni = 0; ni < 4; ++ni) {
                int gn = n0 + wn * 64 + ni * 16 + (lane & 15);
                if (gn >= N) continue;
                float v = acc[mi][ni][r] * alpha;
                if (bias) v += bias[gn];
                if (EPI == 3) {
                    int c = gn >> 6, e = gn & 63;
                    __hip_bfloat16 bv = __float2bfloat16(v);
                    if (c == 0)      qb_[(long)gm * DD + zz * 64 + e] = bv;
                    else if (c == 1) kb_[(long)gm * DD + zz * 64 + e] = bv;
                    else             vtb[(((long)(bq * NHH + zz)) * 128 + e) * APAD + sq] = bv;
                } else if (OUTBF) {
                    ((__hip_bfloat16*)Cb)[(long)gm * ldc + gn] = __float2bfloat16(v);
                } else {
                    ((float*)Cb)[(long)gm * ldc + gn] = v;
                }
            }
        }
    }
}

// ---------------- LayerNorm: fp32 in, bf16 out ----------------
__global__ __launch_bounds__(256) void ln_kernel(
    const float* __restrict__ X, const float* __restrict__ g,
    const float* __restrict__ b, __hip_bfloat16* __restrict__ H)
{
    const long row = blockIdx.x;
    const float* x = X + row * DD;
    const int t = threadIdx.x;
    float v[3];
    float s = 0.f, s2 = 0.f;
    #pragma unroll
    for (int i = 0; i < 3; ++i) {
        v[i] = x[t + i * 256];
        s += v[i]; s2 += v[i] * v[i];
    }
    #pragma unroll
    for (int off = 1; off < 64; off <<= 1) {
        s  += __shfl_xor(s,  off);
        s2 += __shfl_xor(s2, off);
    }
    __shared__ float red[2][4];
    const int lane = t & 63, w = t >> 6;
    if (lane == 0) { red[0][w] = s; red[1][w] = s2; }
    __syncthreads();
    float S1 = red[0][0] + red[0][1] + red[0][2] + red[0][3];
    float S2 = red[1][0] + red[1][1] + red[1][2] + red[1][3];
    float mu  = S1 * (1.0f / 768.0f);
    float var = S2 * (1.0f / 768.0f) - mu * mu;
    float rs  = rsqrtf(var + 1e-5f);
    __hip_bfloat16* h = H + row * DD;
    #pragma unroll
    for (int i = 0; i < 3; ++i) {
        int c = t + i * 256;
        h[c] = __float2bfloat16((v[i] - mu) * rs * g[c] + b[c]);
    }
}

// ---------------- softmax: scores bf16[ld=SLD] -> attn bf16[ld=APAD], zero-padded ----------------
__global__ __launch_bounds__(256) void softmax_kernel(
    const __hip_bfloat16* __restrict__ Sc, __hip_bfloat16* __restrict__ At, int nrows)
{
    int row = blockIdx.x * 4 + (threadIdx.x >> 6);
    if (row >= nrows) return;
    const __hip_bfloat16* p = Sc + (long)row * SLD;
    __hip_bfloat16* o = At + (long)row * APAD;
    const int t = threadIdx.x & 63;
    float vals[4];
    float mx = -1e30f;
    #pragma unroll
    for (int i = 0; i < 4; ++i) {
        int c = t + i * 64;
        vals[i] = (c < SS) ? __bfloat162float(p[c]) : -1e30f;
        mx = fmaxf(mx, vals[i]);
    }
    #pragma unroll
    for (int off = 1; off < 64; off <<= 1) mx = fmaxf(mx, __shfl_xor(mx, off));
    float sum = 0.f;
    #pragma unroll
    for (int i = 0; i < 4; ++i) {
        vals[i] = expf(vals[i] - mx);
        sum += vals[i];
    }
    #pragma unroll
    for (int off = 1; off < 64; off <<= 1) sum += __shfl_xor(sum, off);
    float inv = 1.0f / sum;
    #pragma unroll
    for (int i = 0; i < 4; ++i) {
        int c = t + i * 64;
        o[c] = __float2bfloat16((c < SS) ? vals[i] * inv : 0.0f);
    }
}

// ---------------- patchify: [B,C,H,W] f32 -> [B*196, 768] bf16 ----------------
__global__ void patchify_kernel(const float* __restrict__ img, __hip_bfloat16* __restrict__ patches)
{
    long idx = (long)blockIdx.x * 256 + threadIdx.x;
    const long total = (long)NB * NPAT * DD;
    if (idx >= total) return;
    int k  = (int)(idx % DD);
    long mp = idx / DD;
    int p  = (int)(mp % NPAT);
    long b = mp / NPAT;
    int c = k >> 8;
    int i = (k >> 4) & 15;
    int j = k & 15;
    int pr = p / 14, pc = p % 14;
    int hh = pr * 16 + i, ww = pc * 16 + j;
    patches[idx] = __float2bfloat16(img[((b * 3 + c) * 224 + hh) * 224 + ww]);
}

// ---------------- assemble x = concat(cls, tokens) + pos (fp32) ----------------
__global__ void assemble_kernel(const float* __restrict__ tok, const float* __restrict__ cls,
                                const float* __restrict__ pos, float* __restrict__ X)
{
    long idx = (long)blockIdx.x * 256 + threadIdx.x;
    if (idx >= NX) return;
    int d  = (int)(idx % DD);
    long bs = idx / DD;
    int s  = (int)(bs % SS);
    long b = bs / SS;
    float v = (s == 0) ? cls[d] : tok[(b * NPAT + s - 1) * DD + d];
    X[idx] = v + pos[(long)s * DD + d];
}

// ---------------- fp32 -> bf16 conversion (n multiple of 4) ----------------
__global__ void f2b_kernel(const float* __restrict__ src, __hip_bfloat16* __restrict__ dst, long n4)
{
    long i = (long)blockIdx.x * 256 + threadIdx.x;
    if (i >= n4) return;
    float4 v = *reinterpret_cast<const float4*>(&src[i * 4]);
    __hip_bfloat16 o[4] = { __float2bfloat16(v.x), __float2bfloat16(v.y),
                            __float2bfloat16(v.z), __float2bfloat16(v.w) };
    *reinterpret_cast<uint2*>(&dst[i * 4]) = *reinterpret_cast<const uint2*>(o);
}

// ---------------- pack per-head qkv weights: wqkv[12][256][64] rows 0..191, bqkv[12][192] ----------------
__global__ void qkvpack_kernel(const float* __restrict__ qw, const float* __restrict__ kw,
                               const float* __restrict__ vw, const float* __restrict__ qb,
                               const float* __restrict__ kb, const float* __restrict__ vb,
                               __hip_bfloat16* __restrict__ W, float* __restrict__ Bv)
{
    int idx = blockIdx.x * 256 + threadIdx.x;   // over 12*192*64
    if (idx >= NHH * 192 * 64) return;
    int d = idx & 63;
    int rest = idx >> 6;
    int j = rest % 192;
    int h = rest / 192;
    int c = j >> 6, e = j & 63;
    const float* src = (c == 0 ? qw : c == 1 ? kw : vw) + ((long)h * 64 + e) * 64 + d;
    W[((long)h * 256 + j) * 64 + d] = __float2bfloat16(*src);
    if (d == 0) {
        const float* sb = (c == 0 ? qb : c == 1 ? kb : vb) + h * 64 + e;
        Bv[h * 192 + j] = *sb;
    }
}

// ---------------- host ----------------
extern "C" void kernel_launch(void* const* d_in, const int* in_sizes, int n_in,
                              void* d_out, int out_size, void* d_ws, size_t ws_size,
                              hipStream_t stream)
{
    const float* images   = (const float*)d_in[0];
    const float* mapper_w = (const float*)d_in[1];
    const float* mapper_b = (const float*)d_in[2];
    const float* cls      = (const float*)d_in[3];
    const float* pos      = (const float*)d_in[4];
    const float* ln1_g    = (const float*)d_in[5];
    const float* ln1_b    = (const float*)d_in[6];
    const float* qw       = (const float*)d_in[7];
    const float* qb       = (const float*)d_in[8];
    const float* kw       = (const float*)d_in[9];
    const float* kb       = (const float*)d_in[10];
    const float* vw       = (const float*)d_in[11];
    const float* vb       = (const float*)d_in[12];
    const float* ow       = (const float*)d_in[13];
    const float* ob       = (const float*)d_in[14];
    const float* ln2_g    = (const float*)d_in[15];
    const float* ln2_b    = (const float*)d_in[16];
    const float* w1       = (const float*)d_in[17];
    const float* b1       = (const float*)d_in[18];
    const float* w2       = (const float*)d_in[19];
    const float* b2       = (const float*)d_in[20];
    float* out = (float*)d_out;

    // ---- workspace (bump allocator, 256B aligned)
    char* p0 = (char*)d_ws;
    char* pp = p0;
    auto alloc = [&](size_t bytes) { char* r = pp; pp += (bytes + 255) & ~(size_t)255; return r; };

    float*           x      = (float*)          alloc(NX * 4);
    __hip_bfloat16*  h16    = (__hip_bfloat16*) alloc((size_t)PADM2 * DD * 2);
    __hip_bfloat16*  ctx16  = (__hip_bfloat16*) alloc((size_t)PADM2 * DD * 2);
    __hip_bfloat16*  wbuf16 = (__hip_bfloat16*) alloc((size_t)(DD*DD + (size_t)FFF*DD*2) * 2);
    __hip_bfloat16*  wqkv16 = (__hip_bfloat16*) alloc((size_t)NHH * 256 * 64 * 2);
    float*           bqkv   = (float*)          alloc((size_t)NHH * 192 * 4);
    __hip_bfloat16*  qbuf   = (__hip_bfloat16*) alloc((size_t)PADM * DD * 2);
    __hip_bfloat16*  kbuf   = (__hip_bfloat16*) alloc((size_t)PADM * DD * 2);
    __hip_bfloat16*  vt     = (__hip_bfloat16*) alloc((size_t)NB * NHH * 128 * APAD * 2);
    __hip_bfloat16*  attn   = (__hip_bfloat16*) alloc(((size_t)NB * NHH * SS + 64) * APAD * 2);
    // shared region: scores (62.9MB) | mid16 (78.6MB) | patches+tokens (57.9MB)
    char*            big    = alloc((size_t)PADM2 * FFF * 2);

    if ((size_t)(pp - p0) > ws_size) return;

    __hip_bfloat16* scores16  = (__hip_bfloat16*)big;
    __hip_bfloat16* mid16     = (__hip_bfloat16*)big;
    __hip_bfloat16* patches16 = (__hip_bfloat16*)big;
    float*          tokens    = (float*)(big + (((size_t)NB * NPAT * DD * 2 + 255) & ~(size_t)255));

    __hip_bfloat16* ow16 = wbuf16;
    __hip_bfloat16* w116 = wbuf16 + (size_t)DD * DD;
    __hip_bfloat16* w216 = w116 + (size_t)FFF * DD;

    // ---- setup: patchify + mapper (256-tile MFMA) + assemble
    {
        long n = (long)NB * NPAT * DD;
        patchify_kernel<<<dim3((n + 255) / 256), dim3(256), 0, stream>>>(images, patches16);
        f2b_kernel<<<dim3((DD * DD / 4 + 255) / 256), dim3(256), 0, stream>>>(mapper_w, w116, DD * DD / 4);
        gemm_mfma256<0, false><<<dim3(DD / 256, (NB * NPAT) / 256), dim3(512), 0, stream>>>(
            patches16, DD, w116, DD, tokens, DD, mapper_b, nullptr, 0, nullptr,
            NB * NPAT, DD, DD);
        assemble_kernel<<<dim3((NX + 255) / 256), dim3(256), 0, stream>>>(tokens, cls, pos, x);
    }

    const int MT  = (TOK + 127) / 128;   // 99
    const int MT2 = (TOK + 255) / 256;   // 50

    for (int l = 0; l < 12; ++l) {
        // ---- weight prep for this layer
        f2b_kernel<<<dim3((DD * DD / 4 + 255) / 256), dim3(256), 0, stream>>>(
            ow + (long)l * DD * DD, ow16, DD * DD / 4);
        f2b_kernel<<<dim3((FFF * DD / 4 + 255) / 256), dim3(256), 0, stream>>>(
            w1 + (long)l * FFF * DD, w116, FFF * DD / 4);
        f2b_kernel<<<dim3((FFF * DD / 4 + 255) / 256), dim3(256), 0, stream>>>(
            w2 + (long)l * FFF * DD, w216, FFF * DD / 4);
        qkvpack_kernel<<<dim3((NHH * 192 * 64 + 255) / 256), dim3(256), 0, stream>>>(
            qw + (long)l * NHH * DHH * DHH, kw + (long)l * NHH * DHH * DHH,
            vw + (long)l * NHH * DHH * DHH,
            qb + (long)l * DD, kb + (long)l * DD, vb + (long)l * DD,
            wqkv16, bqkv);

        // ---- LN1 -> h16
        ln_kernel<<<dim3(TOK), dim3(256), 0, stream>>>(x, ln1_g + l * DD, ln1_b + l * DD, h16);

        // ---- QKV: batched per head, scatter epilogue (q,k row-major; v transposed)
        gemm_mfma<3, true><<<dim3(2, MT, NHH), dim3(256), 0, stream>>>(
            h16, DD, 64, 0,
            wqkv16, 64, (long)256 * 64, 0,
            nullptr, 0, 0, 0,
            bqkv, 192, 0,
            nullptr, 0, nullptr,
            qbuf, kbuf, vt,
            TOK, 192, 64, 1, 1.0f);

        // ---- scores = q k^T / 4096  (z = b*12+h)
        gemm_mfma<0, true><<<dim3(2, 2, NB * NHH), dim3(256), 0, stream>>>(
            qbuf, DD, (long)SS * DD, 64,
            kbuf, DD, (long)SS * DD, 64,
            scores16, SLD, (long)NHH * SS * SLD, (long)SS * SLD,
            nullptr, 0, 0,
            nullptr, 0, nullptr, nullptr, nullptr, nullptr,
            SS, SS, 64, NHH, 1.0f / 4096.0f);

        // ---- softmax -> attn (bf16, zero-padded to APAD)
        {
            int nrows = NB * NHH * SS;
            softmax_kernel<<<dim3((nrows + 3) / 4), dim3(256), 0, stream>>>(scores16, attn, nrows);
        }

        // ---- ctx = attn @ v  (NT with vt; z = b*12+h)
        gemm_mfma<0, true><<<dim3(1, 2, NB * NHH), dim3(256), 0, stream>>>(
            attn, APAD, (long)NHH * SS * APAD, (long)SS * APAD,
            vt, APAD, (long)NHH * 128 * APAD, (long)128 * APAD,
            ctx16, DD, (long)SS * DD, 64,
            nullptr, 0, 0,
            nullptr, 0, nullptr, nullptr, nullptr, nullptr,
            SS, DHH, APAD, NHH, 1.0f);

        // ---- x = x + ctx @ ow^T + ob  (256-tile)
        gemm_mfma256<1, false><<<dim3(DD / 256, MT2), dim3(512), 0, stream>>>(
            ctx16, DD, ow16, DD, x, DD, ob + l * DD, x, DD, nullptr,
            TOK, DD, DD);

        // ---- LN2 -> h16
        ln_kernel<<<dim3(TOK), dim3(256), 0, stream>>>(x, ln2_g + l * DD, ln2_b + l * DD, h16);

        // ---- mid = gelu(h @ w1^T + b1)  (256-tile)
        gemm_mfma256<2, true><<<dim3(FFF / 256, MT2), dim3(512), 0, stream>>>(
            h16, DD, w116, DD, mid16, FFF, b1 + l * FFF, nullptr, 0, nullptr,
            TOK, FFF, DD);

        // ---- x = x + mid @ w2^T + b2 (+ fused extraction)  (256-tile)
        int slot = (l == 2) ? 0 : (l == 5) ? 1 : (l == 8) ? 2 : (l == 11) ? 3 : -1;
        float* o2 = (slot >= 0) ? out + (long)slot * NX : nullptr;
        gemm_mfma256<1, false><<<dim3(DD / 256, MT2), dim3(512), 0, stream>>>(
            mid16, FFF, w216, FFF, x, DD, b2 + l * DD, x, DD, o2,
            TOK, DD, FFF);
    }
}

// Round 5
// 8195.824 us; speedup vs baseline: 3.5839x; 1.0301x over previous
//
#include <hip/hip_runtime.h>
#include <hip/hip_bf16.h>
#include <math.h>

// ---------------- problem constants ----------------
static constexpr int NB   = 64;           // batch
static constexpr int SS   = 197;          // tokens
static constexpr int DD   = 768;          // hidden
static constexpr int NHH  = 12;           // heads
static constexpr int DHH  = 64;           // head dim
static constexpr int FFF  = 3072;         // mlp hidden
static constexpr int TOK  = NB * SS;      // 12608
static constexpr int NPAT = 196;          // patches per image
static constexpr int PADM = 12672;        // TOK padded to multiple of 128
static constexpr int PADM2= 12800;        // TOK padded to multiple of 256
static constexpr long NX  = (long)TOK * DD;  // 9,682,944
static constexpr int SLD  = 208;          // scores row pitch (bf16, 16B aligned)
static constexpr int APAD = 256;          // attn row pitch (K-padded, zero-filled)

typedef __attribute__((ext_vector_type(8))) short bf16x8;
typedef __attribute__((ext_vector_type(4))) float f32x4;

__device__ inline void gll16(const __hip_bfloat16* g, __hip_bfloat16* l) {
    __builtin_amdgcn_global_load_lds(
        (const __attribute__((address_space(1))) void*)g,
        (__attribute__((address_space(3))) void*)l, 16, 0, 0);
}

// =====================================================================
// 256x256 tile bf16 MFMA GEMM, BK=64, 8 waves (2Mx4N), 2-buffer LDS,
// 4 phases per K-tile, counted vmcnt(8), XOR bank-swizzle, setprio.
// C = A[M][K] * Bt[N][K]^T (+bias[n]) (+residual) (gelu)
// LDS slot layout per buffer: [0]=A rows 0-127, [1]=A rows 128-255,
//                             [2]=B rows 0-127, [3]=B rows 128-255
// Each half-tile slot: 128 rows x 64 cols bf16; 16B-group pg = g ^ (row&7).
// Requires: N,K multiples of 256/64; A/Bt rows readable to tile bounds.
// EPI: 0 none, 1 +residual (opt dup-store out2), 2 gelu
// =====================================================================
template<int EPI, bool OUTBF>
__global__ __launch_bounds__(512, 1) void gemm_mfma256(
    const __hip_bfloat16* __restrict__ A, int lda,
    const __hip_bfloat16* __restrict__ Bt, int ldb,
    void* __restrict__ Cout, int ldc,
    const float* __restrict__ bias,
    const float* __restrict__ Rm, int ldr,
    float* __restrict__ out2,
    int M, int N, int K)
{
    __shared__ __hip_bfloat16 sh[2 * 4 * 8192];   // 131072 B

    // ---- bijective XCD swizzle (m204) on flattened grid
    const int nbx = gridDim.x;
    const int nwg = nbx * gridDim.y;
    int flat = blockIdx.y * nbx + blockIdx.x;
    {
        int q = nwg >> 3, r = nwg & 7;
        int xcd = flat & 7, idx = flat >> 3;
        flat = (xcd < r ? xcd * (q + 1) : r * (q + 1) + (xcd - r) * q) + idx;
    }
    const int m0 = (flat / nbx) * 256;
    const int n0 = (flat % nbx) * 256;

    const int t = threadIdx.x;
    const int wid = t >> 6, lane = t & 63;
    const int wm = wid >> 2, wn = wid & 3;        // 2M x 4N
    const int l15 = lane & 15, x7 = lane & 7, g0 = lane >> 4;
    const int ko0 = (g0 ^ x7) << 3;               // kk=0 read col (elems)
    const int ko1 = ((g0 ^ x7) ^ 4) << 3;         // kk=1
    const int bni = (wn & 1) * 64;                // B local row base within slot

    // staging geometry: thread t covers phys slots t and t+512 of a half-tile
    const int pr   = t >> 3;                      // 0..63
    const int pcol = ((t & 7) ^ (pr & 7)) << 3;   // inverse-swizzled source col

    auto stageA = [&](int buf, int k0) {
        #pragma unroll
        for (int h = 0; h < 2; ++h) {
            const __hip_bfloat16* gsrc = A + (long)(m0 + h * 128 + pr) * lda + k0 + pcol;
            __hip_bfloat16* l = &sh[(buf * 4 + h) * 8192 + t * 8];
            gll16(gsrc, l);
            gll16(gsrc + (long)64 * lda, l + 512 * 8);
        }
    };
    auto stageB = [&](int buf, int k0) {
        #pragma unroll
        for (int h = 0; h < 2; ++h) {
            const __hip_bfloat16* gsrc = Bt + (long)(n0 + h * 128 + pr) * ldb + k0 + pcol;
            __hip_bfloat16* l = &sh[(buf * 4 + 2 + h) * 8192 + t * 8];
            gll16(gsrc, l);
            gll16(gsrc + (long)64 * ldb, l + 512 * 8);
        }
    };

    f32x4 acc[8][4] = {};
    bf16x8 af[4][2], bfr[4][2];

    const int NT = K >> 6;

    // ---- prologue: stage tiles 0,1 (8+8 loads/thread); tile0 must land
    stageA(0, 0); stageB(0, 0);
    stageA(1, 64); stageB(1, 64);
    asm volatile("s_waitcnt vmcnt(8)" ::: "memory");
    __builtin_amdgcn_sched_barrier(0);
    __builtin_amdgcn_s_barrier();
    __builtin_amdgcn_sched_barrier(0);

    for (int kt = 0; kt < NT; ++kt) {
        const int b = kt & 1;
        const bool st2 = (kt + 2 < NT);
        const bool w1n = (kt + 1 < NT);
        const int k2 = (kt + 2) << 6;
        const __hip_bfloat16* Abuf = &sh[(b * 4 + wm) * 8192];
        const __hip_bfloat16* Bbuf = &sh[(b * 4 + 2 + (wn >> 1)) * 8192];

        // ================= P1: read A(mih0)+B(ni01); MFMA q(0,*lo) ==========
        #pragma unroll
        for (int mi = 0; mi < 4; ++mi) {
            af[mi][0] = *reinterpret_cast<const bf16x8*>(Abuf + (mi * 16 + l15) * 64 + ko0);
            af[mi][1] = *reinterpret_cast<const bf16x8*>(Abuf + (mi * 16 + l15) * 64 + ko1);
        }
        #pragma unroll
        for (int ni = 0; ni < 2; ++ni) {
            bfr[ni][0] = *reinterpret_cast<const bf16x8*>(Bbuf + (bni + ni * 16 + l15) * 64 + ko0);
            bfr[ni][1] = *reinterpret_cast<const bf16x8*>(Bbuf + (bni + ni * 16 + l15) * 64 + ko1);
        }
        __builtin_amdgcn_sched_barrier(0);
        __builtin_amdgcn_s_barrier();
        asm volatile("s_waitcnt lgkmcnt(0)" ::: "memory");
        __builtin_amdgcn_sched_barrier(0);
        __builtin_amdgcn_s_setprio(1);
        #pragma unroll
        for (int mi = 0; mi < 4; ++mi) {
            acc[mi][0] = __builtin_amdgcn_mfma_f32_16x16x32_bf16(af[mi][0], bfr[0][0], acc[mi][0], 0, 0, 0);
            acc[mi][0] = __builtin_amdgcn_mfma_f32_16x16x32_bf16(af[mi][1], bfr[0][1], acc[mi][0], 0, 0, 0);
            acc[mi][1] = __builtin_amdgcn_mfma_f32_16x16x32_bf16(af[mi][0], bfr[1][0], acc[mi][1], 0, 0, 0);
            acc[mi][1] = __builtin_amdgcn_mfma_f32_16x16x32_bf16(af[mi][1], bfr[1][1], acc[mi][1], 0, 0, 0);
        }
        __builtin_amdgcn_s_setprio(0);
        __builtin_amdgcn_sched_barrier(0);
        __builtin_amdgcn_s_barrier();

        // ================= P2: read B(ni23); MFMA q(0,*hi) ==================
        #pragma unroll
        for (int ni = 2; ni < 4; ++ni) {
            bfr[ni][0] = *reinterpret_cast<const bf16x8*>(Bbuf + (bni + ni * 16 + l15) * 64 + ko0);
            bfr[ni][1] = *reinterpret_cast<const bf16x8*>(Bbuf + (bni + ni * 16 + l15) * 64 + ko1);
        }
        __builtin_amdgcn_sched_barrier(0);
        __builtin_amdgcn_s_barrier();
        asm volatile("s_waitcnt lgkmcnt(0)" ::: "memory");
        __builtin_amdgcn_sched_barrier(0);
        __builtin_amdgcn_s_setprio(1);
        #pragma unroll
        for (int mi = 0; mi < 4; ++mi) {
            acc[mi][2] = __builtin_amdgcn_mfma_f32_16x16x32_bf16(af[mi][0], bfr[2][0], acc[mi][2], 0, 0, 0);
            acc[mi][2] = __builtin_amdgcn_mfma_f32_16x16x32_bf16(af[mi][1], bfr[2][1], acc[mi][2], 0, 0, 0);
            acc[mi][3] = __builtin_amdgcn_mfma_f32_16x16x32_bf16(af[mi][0], bfr[3][0], acc[mi][3], 0, 0, 0);
            acc[mi][3] = __builtin_amdgcn_mfma_f32_16x16x32_bf16(af[mi][1], bfr[3][1], acc[mi][3], 0, 0, 0);
        }
        __builtin_amdgcn_s_setprio(0);
        __builtin_amdgcn_sched_barrier(0);
        __builtin_amdgcn_s_barrier();

        // ===== P3: read A(mih1); stage B(kt+2) into this buf; MFMA q(1,*lo) ==
        #pragma unroll
        for (int mi = 0; mi < 4; ++mi) {
            af[mi][0] = *reinterpret_cast<const bf16x8*>(Abuf + (64 + mi * 16 + l15) * 64 + ko0);
            af[mi][1] = *reinterpret_cast<const bf16x8*>(Abuf + (64 + mi * 16 + l15) * 64 + ko1);
        }
        if (st2) stageB(b, k2);   // B slots last read at P2 (all waves) -> safe
        __builtin_amdgcn_sched_barrier(0);
        __builtin_amdgcn_s_barrier();
        asm volatile("s_waitcnt lgkmcnt(0)" ::: "memory");
        __builtin_amdgcn_sched_barrier(0);
        __builtin_amdgcn_s_setprio(1);
        #pragma unroll
        for (int mi = 0; mi < 4; ++mi) {
            acc[4 + mi][0] = __builtin_amdgcn_mfma_f32_16x16x32_bf16(af[mi][0], bfr[0][0], acc[4 + mi][0], 0, 0, 0);
            acc[4 + mi][0] = __builtin_amdgcn_mfma_f32_16x16x32_bf16(af[mi][1], bfr[0][1], acc[4 + mi][0], 0, 0, 0);
            acc[4 + mi][1] = __builtin_amdgcn_mfma_f32_16x16x32_bf16(af[mi][0], bfr[1][0], acc[4 + mi][1], 0, 0, 0);
            acc[4 + mi][1] = __builtin_amdgcn_mfma_f32_16x16x32_bf16(af[mi][1], bfr[1][1], acc[4 + mi][1], 0, 0, 0);
        }
        __builtin_amdgcn_s_setprio(0);
        __builtin_amdgcn_sched_barrier(0);
        __builtin_amdgcn_s_barrier();

        // ===== P4: stage A(kt+2); MFMA q(1,*hi); counted vmcnt ==============
        if (st2) stageA(b, k2);   // A slots last read at P3 (all waves) -> safe
        __builtin_amdgcn_sched_barrier(0);
        __builtin_amdgcn_s_barrier();
        __builtin_amdgcn_s_setprio(1);
        #pragma unroll
        for (int mi = 0; mi < 4; ++mi) {
            acc[4 + mi][2] = __builtin_amdgcn_mfma_f32_16x16x32_bf16(af[mi][0], bfr[2][0], acc[4 + mi][2], 0, 0, 0);
            acc[4 + mi][2] = __builtin_amdgcn_mfma_f32_16x16x32_bf16(af[mi][1], bfr[2][1], acc[4 + mi][2], 0, 0, 0);
            acc[4 + mi][3] = __builtin_amdgcn_mfma_f32_16x16x32_bf16(af[mi][0], bfr[3][0], acc[4 + mi][3], 0, 0, 0);
            acc[4 + mi][3] = __builtin_amdgcn_mfma_f32_16x16x32_bf16(af[mi][1], bfr[3][1], acc[4 + mi][3], 0, 0, 0);
        }
        __builtin_amdgcn_s_setprio(0);
        __builtin_amdgcn_sched_barrier(0);
        if (st2)      { asm volatile("s_waitcnt vmcnt(8)" ::: "memory"); }  // tile kt+1 landed; kt+2 in flight
        else if (w1n) { asm volatile("s_waitcnt vmcnt(0)" ::: "memory"); }  // tail drain
        __builtin_amdgcn_sched_barrier(0);
        __builtin_amdgcn_s_barrier();
        __builtin_amdgcn_sched_barrier(0);
    }

    // -------- epilogue: C/D layout col=lane&15, row=(lane>>4)*4+r
    #pragma unroll
    for (int mi = 0; mi < 8; ++mi) {
        #pragma unroll
        for (int r = 0; r < 4; ++r) {
            int gm = m0 + wm * 128 + mi * 16 + (lane >> 4) * 4 + r;
            if (gm >= M) continue;
            #pragma unroll
            for (int ni = 0; ni < 4; ++ni) {
                int gn = n0 + wn * 64 + ni * 16 + (lane & 15);
                float v = acc[mi][ni][r];
                if (bias) v += bias[gn];
                if (EPI == 1) v += Rm[(long)gm * ldr + gn];
                if (EPI == 2) v = 0.5f * v * (1.0f + erff(v * 0.70710678118654752f));
                if (OUTBF) {
                    ((__hip_bfloat16*)Cout)[(long)gm * ldc + gn] = __float2bfloat16(v);
                } else {
                    ((float*)Cout)[(long)gm * ldc + gn] = v;
                    if (EPI == 1 && out2) out2[(long)gm * ldc + gn] = v;
                }
            }
        }
    }
}

// =====================================================================
// 128x128 tile MFMA GEMM (attention-sized matmuls), m97 structure, batched
// EPI: 0 none, 3 qkv-scatter
// =====================================================================
template<int EPI, bool OUTBF>
__global__ __launch_bounds__(256) void gemm_mfma(
    const __hip_bfloat16* __restrict__ A, int lda, long sAhi, long sAlo,
    const __hip_bfloat16* __restrict__ Bt, int ldb, long sBhi, long sBlo,
    void* __restrict__ Cout, int ldc, long sChi, long sClo,
    const float* __restrict__ bias, long sbhi, long sblo,
    const float* __restrict__ Rm, int ldr,
    float* __restrict__ out2,
    __hip_bfloat16* __restrict__ qb_, __hip_bfloat16* __restrict__ kb_,
    __hip_bfloat16* __restrict__ vtb,
    int M, int N, int K, int innerB, float alpha)
{
    __shared__ __hip_bfloat16 As[128 * 64];
    __shared__ __hip_bfloat16 Bs[128 * 64];

    const int zz  = blockIdx.z;
    const int zhi = zz / innerB, zlo = zz - zhi * innerB;
    A  += zhi * sAhi + zlo * sAlo;
    Bt += zhi * sBhi + zlo * sBlo;
    char* Cb = (char*)Cout;
    if (Cout) Cb += (zhi * sChi + zlo * sClo) * (OUTBF ? 2 : 4);
    if (bias) bias += zhi * sbhi + zlo * sblo;

    const int t = threadIdx.x;
    const int wid = t >> 6, lane = t & 63;
    const int wm = wid >> 1, wn = wid & 1;
    const int m0 = blockIdx.y * 128, n0 = blockIdx.x * 128;

    const int srow = t >> 3;
    const int scol = (t & 7) * 8;

    f32x4 acc[4][4] = {};

    for (int k0 = 0; k0 < K; k0 += 64) {
        #pragma unroll
        for (int i = 0; i < 4; ++i) {
            const __hip_bfloat16* ga = A + (long)(m0 + i * 32 + srow) * lda + k0 + scol;
            __hip_bfloat16* la = As + (i * 256 + wid * 64) * 8;
            gll16(ga, la);
            const __hip_bfloat16* gb = Bt + (long)(n0 + i * 32 + srow) * ldb + k0 + scol;
            __hip_bfloat16* lb = Bs + (i * 256 + wid * 64) * 8;
            gll16(gb, lb);
        }
        asm volatile("s_waitcnt vmcnt(0)" ::: "memory");
        __syncthreads();

        #pragma unroll
        for (int kk = 0; kk < 2; ++kk) {
            bf16x8 af[4], bfr[4];
            #pragma unroll
            for (int mi = 0; mi < 4; ++mi)
                af[mi] = *reinterpret_cast<const bf16x8*>(
                    &As[(wm * 64 + mi * 16 + (lane & 15)) * 64 + kk * 32 + (lane >> 4) * 8]);
            #pragma unroll
            for (int ni = 0; ni < 4; ++ni)
                bfr[ni] = *reinterpret_cast<const bf16x8*>(
                    &Bs[(wn * 64 + ni * 16 + (lane & 15)) * 64 + kk * 32 + (lane >> 4) * 8]);
            #pragma unroll
            for (int mi = 0; mi < 4; ++mi)
                #pragma unroll
                for (int ni = 0; ni < 4; ++ni)
                    acc[mi][ni] = __builtin_amdgcn_mfma_f32_16x16x32_bf16(
                        af[mi], bfr[ni], acc[mi][ni], 0, 0, 0);
        }
        __syncthreads();
    }

    #pragma unroll
    for (int mi = 0; mi < 4; ++mi) {
        #pragma unroll
        for (int r = 0; r < 4; ++r) {
            int gm = m0 + wm * 64 + mi * 16 + (lane >> 4) * 4 + r;
            if (gm >= M) continue;
            int bq = 0, sq = 0;
            if (EPI == 3) { bq = gm / 197; sq = gm - bq * 197; }
            #pragma unroll
            for (int ni = 0; ni < 4; ++ni) {
                int gn = n0 + wn * 64 + ni * 16 + (lane & 15);
                if (gn >= N) continue;
                float v = acc[mi][ni][r] * alpha;
                if (bias) v += bias[gn];
                if (EPI == 3) {
                    int c = gn >> 6, e = gn & 63;
                    __hip_bfloat16 bv = __float2bfloat16(v);
                    if (c == 0)      qb_[(long)gm * DD + zz * 64 + e] = bv;
                    else if (c == 1) kb_[(long)gm * DD + zz * 64 + e] = bv;
                    else             vtb[(((long)(bq * NHH + zz)) * 128 + e) * APAD + sq] = bv;
                } else if (OUTBF) {
                    ((__hip_bfloat16*)Cb)[(long)gm * ldc + gn] = __float2bfloat16(v);
                } else {
                    ((float*)Cb)[(long)gm * ldc + gn] = v;
                }
            }
        }
    }
}

// ---------------- LayerNorm: fp32 in, bf16 out ----------------
__global__ __launch_bounds__(256) void ln_kernel(
    const float* __restrict__ X, const float* __restrict__ g,
    const float* __restrict__ b, __hip_bfloat16* __restrict__ H)
{
    const long row = blockIdx.x;
    const float* x = X + row * DD;
    const int t = threadIdx.x;
    float v[3];
    float s = 0.f, s2 = 0.f;
    #pragma unroll
    for (int i = 0; i < 3; ++i) {
        v[i] = x[t + i * 256];
        s += v[i]; s2 += v[i] * v[i];
    }
    #pragma unroll
    for (int off = 1; off < 64; off <<= 1) {
        s  += __shfl_xor(s,  off);
        s2 += __shfl_xor(s2, off);
    }
    __shared__ float red[2][4];
    const int lane = t & 63, w = t >> 6;
    if (lane == 0) { red[0][w] = s; red[1][w] = s2; }
    __syncthreads();
    float S1 = red[0][0] + red[0][1] + red[0][2] + red[0][3];
    float S2 = red[1][0] + red[1][1] + red[1][2] + red[1][3];
    float mu  = S1 * (1.0f / 768.0f);
    float var = S2 * (1.0f / 768.0f) - mu * mu;
    float rs  = rsqrtf(var + 1e-5f);
    __hip_bfloat16* h = H + row * DD;
    #pragma unroll
    for (int i = 0; i < 3; ++i) {
        int c = t + i * 256;
        h[c] = __float2bfloat16((v[i] - mu) * rs * g[c] + b[c]);
    }
}

// ---------------- softmax: scores bf16[ld=SLD] -> attn bf16[ld=APAD], zero-padded ----------------
__global__ __launch_bounds__(256) void softmax_kernel(
    const __hip_bfloat16* __restrict__ Sc, __hip_bfloat16* __restrict__ At, int nrows)
{
    int row = blockIdx.x * 4 + (threadIdx.x >> 6);
    if (row >= nrows) return;
    const __hip_bfloat16* p = Sc + (long)row * SLD;
    __hip_bfloat16* o = At + (long)row * APAD;
    const int t = threadIdx.x & 63;
    float vals[4];
    float mx = -1e30f;
    #pragma unroll
    for (int i = 0; i < 4; ++i) {
        int c = t + i * 64;
        vals[i] = (c < SS) ? __bfloat162float(p[c]) : -1e30f;
        mx = fmaxf(mx, vals[i]);
    }
    #pragma unroll
    for (int off = 1; off < 64; off <<= 1) mx = fmaxf(mx, __shfl_xor(mx, off));
    float sum = 0.f;
    #pragma unroll
    for (int i = 0; i < 4; ++i) {
        vals[i] = expf(vals[i] - mx);
        sum += vals[i];
    }
    #pragma unroll
    for (int off = 1; off < 64; off <<= 1) sum += __shfl_xor(sum, off);
    float inv = 1.0f / sum;
    #pragma unroll
    for (int i = 0; i < 4; ++i) {
        int c = t + i * 64;
        o[c] = __float2bfloat16((c < SS) ? vals[i] * inv : 0.0f);
    }
}

// ---------------- patchify: [B,C,H,W] f32 -> [B*196, 768] bf16 ----------------
__global__ void patchify_kernel(const float* __restrict__ img, __hip_bfloat16* __restrict__ patches)
{
    long idx = (long)blockIdx.x * 256 + threadIdx.x;
    const long total = (long)NB * NPAT * DD;
    if (idx >= total) return;
    int k  = (int)(idx % DD);
    long mp = idx / DD;
    int p  = (int)(mp % NPAT);
    long b = mp / NPAT;
    int c = k >> 8;
    int i = (k >> 4) & 15;
    int j = k & 15;
    int pr = p / 14, pc = p % 14;
    int hh = pr * 16 + i, ww = pc * 16 + j;
    patches[idx] = __float2bfloat16(img[((b * 3 + c) * 224 + hh) * 224 + ww]);
}

// ---------------- assemble x = concat(cls, tokens) + pos (fp32) ----------------
__global__ void assemble_kernel(const float* __restrict__ tok, const float* __restrict__ cls,
                                const float* __restrict__ pos, float* __restrict__ X)
{
    long idx = (long)blockIdx.x * 256 + threadIdx.x;
    if (idx >= NX) return;
    int d  = (int)(idx % DD);
    long bs = idx / DD;
    int s  = (int)(bs % SS);
    long b = bs / SS;
    float v = (s == 0) ? cls[d] : tok[(b * NPAT + s - 1) * DD + d];
    X[idx] = v + pos[(long)s * DD + d];
}

// ---------------- fp32 -> bf16 conversion (n multiple of 4) ----------------
__global__ void f2b_kernel(const float* __restrict__ src, __hip_bfloat16* __restrict__ dst, long n4)
{
    long i = (long)blockIdx.x * 256 + threadIdx.x;
    if (i >= n4) return;
    float4 v = *reinterpret_cast<const float4*>(&src[i * 4]);
    __hip_bfloat16 o[4] = { __float2bfloat16(v.x), __float2bfloat16(v.y),
                            __float2bfloat16(v.z), __float2bfloat16(v.w) };
    *reinterpret_cast<uint2*>(&dst[i * 4]) = *reinterpret_cast<const uint2*>(o);
}

// ---------------- pack per-head qkv weights: wqkv[12][256][64] rows 0..191, bqkv[12][192] ----------------
__global__ void qkvpack_kernel(const float* __restrict__ qw, const float* __restrict__ kw,
                               const float* __restrict__ vw, const float* __restrict__ qb,
                               const float* __restrict__ kb, const float* __restrict__ vb,
                               __hip_bfloat16* __restrict__ W, float* __restrict__ Bv)
{
    int idx = blockIdx.x * 256 + threadIdx.x;   // over 12*192*64
    if (idx >= NHH * 192 * 64) return;
    int d = idx & 63;
    int rest = idx >> 6;
    int j = rest % 192;
    int h = rest / 192;
    int c = j >> 6, e = j & 63;
    const float* src = (c == 0 ? qw : c == 1 ? kw : vw) + ((long)h * 64 + e) * 64 + d;
    W[((long)h * 256 + j) * 64 + d] = __float2bfloat16(*src);
    if (d == 0) {
        const float* sb = (c == 0 ? qb : c == 1 ? kb : vb) + h * 64 + e;
        Bv[h * 192 + j] = *sb;
    }
}

// ---------------- host ----------------
extern "C" void kernel_launch(void* const* d_in, const int* in_sizes, int n_in,
                              void* d_out, int out_size, void* d_ws, size_t ws_size,
                              hipStream_t stream)
{
    const float* images   = (const float*)d_in[0];
    const float* mapper_w = (const float*)d_in[1];
    const float* mapper_b = (const float*)d_in[2];
    const float* cls      = (const float*)d_in[3];
    const float* pos      = (const float*)d_in[4];
    const float* ln1_g    = (const float*)d_in[5];
    const float* ln1_b    = (const float*)d_in[6];
    const float* qw       = (const float*)d_in[7];
    const float* qb       = (const float*)d_in[8];
    const float* kw       = (const float*)d_in[9];
    const float* kb       = (const float*)d_in[10];
    const float* vw       = (const float*)d_in[11];
    const float* vb       = (const float*)d_in[12];
    const float* ow       = (const float*)d_in[13];
    const float* ob       = (const float*)d_in[14];
    const float* ln2_g    = (const float*)d_in[15];
    const float* ln2_b    = (const float*)d_in[16];
    const float* w1       = (const float*)d_in[17];
    const float* b1       = (const float*)d_in[18];
    const float* w2       = (const float*)d_in[19];
    const float* b2       = (const float*)d_in[20];
    float* out = (float*)d_out;

    // ---- workspace (bump allocator, 256B aligned)
    char* p0 = (char*)d_ws;
    char* pp = p0;
    auto alloc = [&](size_t bytes) { char* r = pp; pp += (bytes + 255) & ~(size_t)255; return r; };

    float*           x      = (float*)          alloc(NX * 4);
    __hip_bfloat16*  h16    = (__hip_bfloat16*) alloc((size_t)PADM2 * DD * 2);
    __hip_bfloat16*  ctx16  = (__hip_bfloat16*) alloc((size_t)PADM2 * DD * 2);
    __hip_bfloat16*  wbuf16 = (__hip_bfloat16*) alloc((size_t)(DD*DD + (size_t)FFF*DD*2) * 2);
    __hip_bfloat16*  wqkv16 = (__hip_bfloat16*) alloc((size_t)NHH * 256 * 64 * 2);
    float*           bqkv   = (float*)          alloc((size_t)NHH * 192 * 4);
    __hip_bfloat16*  qbuf   = (__hip_bfloat16*) alloc((size_t)PADM * DD * 2);
    __hip_bfloat16*  kbuf   = (__hip_bfloat16*) alloc((size_t)PADM * DD * 2);
    __hip_bfloat16*  vt     = (__hip_bfloat16*) alloc((size_t)NB * NHH * 128 * APAD * 2);
    __hip_bfloat16*  attn   = (__hip_bfloat16*) alloc(((size_t)NB * NHH * SS + 64) * APAD * 2);
    // shared region: scores (62.9MB) | mid16 (78.6MB) | patches+tokens (57.9MB)
    char*            big    = alloc((size_t)PADM2 * FFF * 2);

    if ((size_t)(pp - p0) > ws_size) return;

    __hip_bfloat16* scores16  = (__hip_bfloat16*)big;
    __hip_bfloat16* mid16     = (__hip_bfloat16*)big;
    __hip_bfloat16* patches16 = (__hip_bfloat16*)big;
    float*          tokens    = (float*)(big + (((size_t)NB * NPAT * DD * 2 + 255) & ~(size_t)255));

    __hip_bfloat16* ow16 = wbuf16;
    __hip_bfloat16* w116 = wbuf16 + (size_t)DD * DD;
    __hip_bfloat16* w216 = w116 + (size_t)FFF * DD;

    // ---- setup: patchify + mapper (256-tile MFMA) + assemble
    {
        long n = (long)NB * NPAT * DD;
        patchify_kernel<<<dim3((n + 255) / 256), dim3(256), 0, stream>>>(images, patches16);
        f2b_kernel<<<dim3((DD * DD / 4 + 255) / 256), dim3(256), 0, stream>>>(mapper_w, w116, DD * DD / 4);
        gemm_mfma256<0, false><<<dim3(DD / 256, (NB * NPAT) / 256), dim3(512), 0, stream>>>(
            patches16, DD, w116, DD, tokens, DD, mapper_b, nullptr, 0, nullptr,
            NB * NPAT, DD, DD);
        assemble_kernel<<<dim3((NX + 255) / 256), dim3(256), 0, stream>>>(tokens, cls, pos, x);
    }

    const int MT  = (TOK + 127) / 128;   // 99
    const int MT2 = (TOK + 255) / 256;   // 50

    for (int l = 0; l < 12; ++l) {
        // ---- weight prep for this layer
        f2b_kernel<<<dim3((DD * DD / 4 + 255) / 256), dim3(256), 0, stream>>>(
            ow + (long)l * DD * DD, ow16, DD * DD / 4);
        f2b_kernel<<<dim3((FFF * DD / 4 + 255) / 256), dim3(256), 0, stream>>>(
            w1 + (long)l * FFF * DD, w116, FFF * DD / 4);
        f2b_kernel<<<dim3((FFF * DD / 4 + 255) / 256), dim3(256), 0, stream>>>(
            w2 + (long)l * FFF * DD, w216, FFF * DD / 4);
        qkvpack_kernel<<<dim3((NHH * 192 * 64 + 255) / 256), dim3(256), 0, stream>>>(
            qw + (long)l * NHH * DHH * DHH, kw + (long)l * NHH * DHH * DHH,
            vw + (long)l * NHH * DHH * DHH,
            qb + (long)l * DD, kb + (long)l * DD, vb + (long)l * DD,
            wqkv16, bqkv);

        // ---- LN1 -> h16
        ln_kernel<<<dim3(TOK), dim3(256), 0, stream>>>(x, ln1_g + l * DD, ln1_b + l * DD, h16);

        // ---- QKV: batched per head, scatter epilogue (q,k row-major; v transposed)
        gemm_mfma<3, true><<<dim3(2, MT, NHH), dim3(256), 0, stream>>>(
            h16, DD, 64, 0,
            wqkv16, 64, (long)256 * 64, 0,
            nullptr, 0, 0, 0,
            bqkv, 192, 0,
            nullptr, 0, nullptr,
            qbuf, kbuf, vt,
            TOK, 192, 64, 1, 1.0f);

        // ---- scores = q k^T / 4096  (z = b*12+h)
        gemm_mfma<0, true><<<dim3(2, 2, NB * NHH), dim3(256), 0, stream>>>(
            qbuf, DD, (long)SS * DD, 64,
            kbuf, DD, (long)SS * DD, 64,
            scores16, SLD, (long)NHH * SS * SLD, (long)SS * SLD,
            nullptr, 0, 0,
            nullptr, 0, nullptr, nullptr, nullptr, nullptr,
            SS, SS, 64, NHH, 1.0f / 4096.0f);

        // ---- softmax -> attn (bf16, zero-padded to APAD)
        {
            int nrows = NB * NHH * SS;
            softmax_kernel<<<dim3((nrows + 3) / 4), dim3(256), 0, stream>>>(scores16, attn, nrows);
        }

        // ---- ctx = attn @ v  (NT with vt; z = b*12+h)
        gemm_mfma<0, true><<<dim3(1, 2, NB * NHH), dim3(256), 0, stream>>>(
            attn, APAD, (long)NHH * SS * APAD, (long)SS * APAD,
            vt, APAD, (long)NHH * 128 * APAD, (long)128 * APAD,
            ctx16, DD, (long)SS * DD, 64,
            nullptr, 0, 0,
            nullptr, 0, nullptr, nullptr, nullptr, nullptr,
            SS, DHH, APAD, NHH, 1.0f);

        // ---- x = x + ctx @ ow^T + ob  (256-tile)
        gemm_mfma256<1, false><<<dim3(DD / 256, MT2), dim3(512), 0, stream>>>(
            ctx16, DD, ow16, DD, x, DD, ob + l * DD, x, DD, nullptr,
            TOK, DD, DD);

        // ---- LN2 -> h16
        ln_kernel<<<dim3(TOK), dim3(256), 0, stream>>>(x, ln2_g + l * DD, ln2_b + l * DD, h16);

        // ---- mid = gelu(h @ w1^T + b1)  (256-tile)
        gemm_mfma256<2, true><<<dim3(FFF / 256, MT2), dim3(512), 0, stream>>>(
            h16, DD, w116, DD, mid16, FFF, b1 + l * FFF, nullptr, 0, nullptr,
            TOK, FFF, DD);

        // ---- x = x + mid @ w2^T + b2 (+ fused extraction)  (256-tile)
        int slot = (l == 2) ? 0 : (l == 5) ? 1 : (l == 8) ? 2 : (l == 11) ? 3 : -1;
        float* o2 = (slot >= 0) ? out + (long)slot * NX : nullptr;
        gemm_mfma256<1, false><<<dim3(DD / 256, MT2), dim3(512), 0, stream>>>(
            mid16, FFF, w216, FFF, x, DD, b2 + l * DD, x, DD, o2,
            TOK, DD, FFF);
    }
}

// Round 7
// 6710.826 us; speedup vs baseline: 4.3769x; 1.2213x over previous
//
#include <hip/hip_runtime.h>
#include <hip/hip_bf16.h>
#include <math.h>

// ---------------- problem constants ----------------
static constexpr int NB   = 64;           // batch
static constexpr int SS   = 197;          // tokens
static constexpr int DD   = 768;          // hidden
static constexpr int NHH  = 12;           // heads
static constexpr int DHH  = 64;           // head dim
static constexpr int FFF  = 3072;         // mlp hidden
static constexpr int TOK  = NB * SS;      // 12608
static constexpr int NPAT = 196;          // patches per image
static constexpr int PADM = 12672;        // TOK padded to multiple of 128
static constexpr int PADM2= 12800;        // TOK padded to multiple of 256
static constexpr long NX  = (long)TOK * DD;  // 9,682,944
static constexpr int APAD = 256;          // vt row pitch (k-slots)

typedef __attribute__((ext_vector_type(8))) short bf16x8;
typedef __attribute__((ext_vector_type(4))) float f32x4;

__device__ inline void gll16(const __hip_bfloat16* g, __hip_bfloat16* l) {
    __builtin_amdgcn_global_load_lds(
        (const __attribute__((address_space(1))) void*)g,
        (__attribute__((address_space(3))) void*)l, 16, 0, 0);
}

// =====================================================================
// 256x256 tile bf16 MFMA GEMM, BK=64, 8 waves (2Mx4N), 2-buffer LDS,
// 4 phases per K-tile, counted vmcnt(8), XOR bank-swizzle, setprio.
// EPI: 0 none, 1 +residual (opt dup-store out2), 2 gelu
// =====================================================================
template<int EPI, bool OUTBF>
__global__ __launch_bounds__(512, 1) void gemm_mfma256(
    const __hip_bfloat16* __restrict__ A, int lda,
    const __hip_bfloat16* __restrict__ Bt, int ldb,
    void* __restrict__ Cout, int ldc,
    const float* __restrict__ bias,
    const float* __restrict__ Rm, int ldr,
    float* __restrict__ out2,
    int M, int N, int K)
{
    __shared__ __hip_bfloat16 sh[2 * 4 * 8192];   // 131072 B

    const int nbx = gridDim.x;
    const int nwg = nbx * gridDim.y;
    int flat = blockIdx.y * nbx + blockIdx.x;
    {
        int q = nwg >> 3, r = nwg & 7;
        int xcd = flat & 7, idx = flat >> 3;
        flat = (xcd < r ? xcd * (q + 1) : r * (q + 1) + (xcd - r) * q) + idx;
    }
    const int m0 = (flat / nbx) * 256;
    const int n0 = (flat % nbx) * 256;

    const int t = threadIdx.x;
    const int wid = t >> 6, lane = t & 63;
    const int wm = wid >> 2, wn = wid & 3;        // 2M x 4N
    const int l15 = lane & 15, x7 = lane & 7, g0 = lane >> 4;
    const int ko0 = (g0 ^ x7) << 3;               // kk=0 read col (elems)
    const int ko1 = ((g0 ^ x7) ^ 4) << 3;         // kk=1
    const int bni = (wn & 1) * 64;

    const int pr   = t >> 3;
    const int pcol = ((t & 7) ^ (pr & 7)) << 3;

    auto stageA = [&](int buf, int k0) {
        #pragma unroll
        for (int h = 0; h < 2; ++h) {
            const __hip_bfloat16* gsrc = A + (long)(m0 + h * 128 + pr) * lda + k0 + pcol;
            __hip_bfloat16* l = &sh[(buf * 4 + h) * 8192 + t * 8];
            gll16(gsrc, l);
            gll16(gsrc + (long)64 * lda, l + 512 * 8);
        }
    };
    auto stageB = [&](int buf, int k0) {
        #pragma unroll
        for (int h = 0; h < 2; ++h) {
            const __hip_bfloat16* gsrc = Bt + (long)(n0 + h * 128 + pr) * ldb + k0 + pcol;
            __hip_bfloat16* l = &sh[(buf * 4 + 2 + h) * 8192 + t * 8];
            gll16(gsrc, l);
            gll16(gsrc + (long)64 * ldb, l + 512 * 8);
        }
    };

    f32x4 acc[8][4] = {};
    bf16x8 af[4][2], bfr[4][2];

    const int NT = K >> 6;

    stageA(0, 0); stageB(0, 0);
    stageA(1, 64); stageB(1, 64);
    asm volatile("s_waitcnt vmcnt(8)" ::: "memory");
    __builtin_amdgcn_sched_barrier(0);
    __builtin_amdgcn_s_barrier();
    __builtin_amdgcn_sched_barrier(0);

    for (int kt = 0; kt < NT; ++kt) {
        const int b = kt & 1;
        const bool st2 = (kt + 2 < NT);
        const bool w1n = (kt + 1 < NT);
        const int k2 = (kt + 2) << 6;
        const __hip_bfloat16* Abuf = &sh[(b * 4 + wm) * 8192];
        const __hip_bfloat16* Bbuf = &sh[(b * 4 + 2 + (wn >> 1)) * 8192];

        // P1
        #pragma unroll
        for (int mi = 0; mi < 4; ++mi) {
            af[mi][0] = *reinterpret_cast<const bf16x8*>(Abuf + (mi * 16 + l15) * 64 + ko0);
            af[mi][1] = *reinterpret_cast<const bf16x8*>(Abuf + (mi * 16 + l15) * 64 + ko1);
        }
        #pragma unroll
        for (int ni = 0; ni < 2; ++ni) {
            bfr[ni][0] = *reinterpret_cast<const bf16x8*>(Bbuf + (bni + ni * 16 + l15) * 64 + ko0);
            bfr[ni][1] = *reinterpret_cast<const bf16x8*>(Bbuf + (bni + ni * 16 + l15) * 64 + ko1);
        }
        __builtin_amdgcn_sched_barrier(0);
        __builtin_amdgcn_s_barrier();
        asm volatile("s_waitcnt lgkmcnt(0)" ::: "memory");
        __builtin_amdgcn_sched_barrier(0);
        __builtin_amdgcn_s_setprio(1);
        #pragma unroll
        for (int mi = 0; mi < 4; ++mi) {
            acc[mi][0] = __builtin_amdgcn_mfma_f32_16x16x32_bf16(af[mi][0], bfr[0][0], acc[mi][0], 0, 0, 0);
            acc[mi][0] = __builtin_amdgcn_mfma_f32_16x16x32_bf16(af[mi][1], bfr[0][1], acc[mi][0], 0, 0, 0);
            acc[mi][1] = __builtin_amdgcn_mfma_f32_16x16x32_bf16(af[mi][0], bfr[1][0], acc[mi][1], 0, 0, 0);
            acc[mi][1] = __builtin_amdgcn_mfma_f32_16x16x32_bf16(af[mi][1], bfr[1][1], acc[mi][1], 0, 0, 0);
        }
        __builtin_amdgcn_s_setprio(0);
        __builtin_amdgcn_sched_barrier(0);
        __builtin_amdgcn_s_barrier();

        // P2
        #pragma unroll
        for (int ni = 2; ni < 4; ++ni) {
            bfr[ni][0] = *reinterpret_cast<const bf16x8*>(Bbuf + (bni + ni * 16 + l15) * 64 + ko0);
            bfr[ni][1] = *reinterpret_cast<const bf16x8*>(Bbuf + (bni + ni * 16 + l15) * 64 + ko1);
        }
        __builtin_amdgcn_sched_barrier(0);
        __builtin_amdgcn_s_barrier();
        asm volatile("s_waitcnt lgkmcnt(0)" ::: "memory");
        __builtin_amdgcn_sched_barrier(0);
        __builtin_amdgcn_s_setprio(1);
        #pragma unroll
        for (int mi = 0; mi < 4; ++mi) {
            acc[mi][2] = __builtin_amdgcn_mfma_f32_16x16x32_bf16(af[mi][0], bfr[2][0], acc[mi][2], 0, 0, 0);
            acc[mi][2] = __builtin_amdgcn_mfma_f32_16x16x32_bf16(af[mi][1], bfr[2][1], acc[mi][2], 0, 0, 0);
            acc[mi][3] = __builtin_amdgcn_mfma_f32_16x16x32_bf16(af[mi][0], bfr[3][0], acc[mi][3], 0, 0, 0);
            acc[mi][3] = __builtin_amdgcn_mfma_f32_16x16x32_bf16(af[mi][1], bfr[3][1], acc[mi][3], 0, 0, 0);
        }
        __builtin_amdgcn_s_setprio(0);
        __builtin_amdgcn_sched_barrier(0);
        __builtin_amdgcn_s_barrier();

        // P3
        #pragma unroll
        for (int mi = 0; mi < 4; ++mi) {
            af[mi][0] = *reinterpret_cast<const bf16x8*>(Abuf + (64 + mi * 16 + l15) * 64 + ko0);
            af[mi][1] = *reinterpret_cast<const bf16x8*>(Abuf + (64 + mi * 16 + l15) * 64 + ko1);
        }
        if (st2) stageB(b, k2);
        __builtin_amdgcn_sched_barrier(0);
        __builtin_amdgcn_s_barrier();
        asm volatile("s_waitcnt lgkmcnt(0)" ::: "memory");
        __builtin_amdgcn_sched_barrier(0);
        __builtin_amdgcn_s_setprio(1);
        #pragma unroll
        for (int mi = 0; mi < 4; ++mi) {
            acc[4 + mi][0] = __builtin_amdgcn_mfma_f32_16x16x32_bf16(af[mi][0], bfr[0][0], acc[4 + mi][0], 0, 0, 0);
            acc[4 + mi][0] = __builtin_amdgcn_mfma_f32_16x16x32_bf16(af[mi][1], bfr[0][1], acc[4 + mi][0], 0, 0, 0);
            acc[4 + mi][1] = __builtin_amdgcn_mfma_f32_16x16x32_bf16(af[mi][0], bfr[1][0], acc[4 + mi][1], 0, 0, 0);
            acc[4 + mi][1] = __builtin_amdgcn_mfma_f32_16x16x32_bf16(af[mi][1], bfr[1][1], acc[4 + mi][1], 0, 0, 0);
        }
        __builtin_amdgcn_s_setprio(0);
        __builtin_amdgcn_sched_barrier(0);
        __builtin_amdgcn_s_barrier();

        // P4
        if (st2) stageA(b, k2);
        __builtin_amdgcn_sched_barrier(0);
        __builtin_amdgcn_s_barrier();
        __builtin_amdgcn_s_setprio(1);
        #pragma unroll
        for (int mi = 0; mi < 4; ++mi) {
            acc[4 + mi][2] = __builtin_amdgcn_mfma_f32_16x16x32_bf16(af[mi][0], bfr[2][0], acc[4 + mi][2], 0, 0, 0);
            acc[4 + mi][2] = __builtin_amdgcn_mfma_f32_16x16x32_bf16(af[mi][1], bfr[2][1], acc[4 + mi][2], 0, 0, 0);
            acc[4 + mi][3] = __builtin_amdgcn_mfma_f32_16x16x32_bf16(af[mi][0], bfr[3][0], acc[4 + mi][3], 0, 0, 0);
            acc[4 + mi][3] = __builtin_amdgcn_mfma_f32_16x16x32_bf16(af[mi][1], bfr[3][1], acc[4 + mi][3], 0, 0, 0);
        }
        __builtin_amdgcn_s_setprio(0);
        __builtin_amdgcn_sched_barrier(0);
        if (st2)      { asm volatile("s_waitcnt vmcnt(8)" ::: "memory"); }
        else if (w1n) { asm volatile("s_waitcnt vmcnt(0)" ::: "memory"); }
        __builtin_amdgcn_sched_barrier(0);
        __builtin_amdgcn_s_barrier();
        __builtin_amdgcn_sched_barrier(0);
    }

    #pragma unroll
    for (int mi = 0; mi < 8; ++mi) {
        #pragma unroll
        for (int r = 0; r < 4; ++r) {
            int gm = m0 + wm * 128 + mi * 16 + (lane >> 4) * 4 + r;
            if (gm >= M) continue;
            #pragma unroll
            for (int ni = 0; ni < 4; ++ni) {
                int gn = n0 + wn * 64 + ni * 16 + (lane & 15);
                float v = acc[mi][ni][r];
                if (bias) v += bias[gn];
                if (EPI == 1) v += Rm[(long)gm * ldr + gn];
                if (EPI == 2) v = 0.5f * v * (1.0f + erff(v * 0.70710678118654752f));
                if (OUTBF) {
                    ((__hip_bfloat16*)Cout)[(long)gm * ldc + gn] = __float2bfloat16(v);
                } else {
                    ((float*)Cout)[(long)gm * ldc + gn] = v;
                    if (EPI == 1 && out2) out2[(long)gm * ldc + gn] = v;
                }
            }
        }
    }
}

// =====================================================================
// 128x128 tile MFMA GEMM — QKV projection with scatter epilogue
// =====================================================================
__global__ __launch_bounds__(256) void gemm_qkv(
    const __hip_bfloat16* __restrict__ A, int lda, long sAlo,
    const __hip_bfloat16* __restrict__ Bt, int ldb, long sBhi,
    const float* __restrict__ bias, long sbhi,
    __hip_bfloat16* __restrict__ qb_, __hip_bfloat16* __restrict__ kb_,
    __hip_bfloat16* __restrict__ vtb,
    int M, int N, int K)
{
    __shared__ __hip_bfloat16 As[128 * 64];
    __shared__ __hip_bfloat16 Bs[128 * 64];

    const int zz = blockIdx.z;
    A  += zz * sAlo;
    Bt += zz * sBhi;
    bias += zz * sbhi;

    const int t = threadIdx.x;
    const int wid = t >> 6, lane = t & 63;
    const int wm = wid >> 1, wn = wid & 1;
    const int m0 = blockIdx.y * 128, n0 = blockIdx.x * 128;

    const int srow = t >> 3;
    const int scol = (t & 7) * 8;

    f32x4 acc[4][4] = {};

    for (int k0 = 0; k0 < K; k0 += 64) {
        #pragma unroll
        for (int i = 0; i < 4; ++i) {
            const __hip_bfloat16* ga = A + (long)(m0 + i * 32 + srow) * lda + k0 + scol;
            __hip_bfloat16* la = As + (i * 256 + wid * 64) * 8;
            gll16(ga, la);
            const __hip_bfloat16* gb = Bt + (long)(n0 + i * 32 + srow) * ldb + k0 + scol;
            __hip_bfloat16* lb = Bs + (i * 256 + wid * 64) * 8;
            gll16(gb, lb);
        }
        asm volatile("s_waitcnt vmcnt(0)" ::: "memory");
        __syncthreads();

        #pragma unroll
        for (int kk = 0; kk < 2; ++kk) {
            bf16x8 af[4], bfr[4];
            #pragma unroll
            for (int mi = 0; mi < 4; ++mi)
                af[mi] = *reinterpret_cast<const bf16x8*>(
                    &As[(wm * 64 + mi * 16 + (lane & 15)) * 64 + kk * 32 + (lane >> 4) * 8]);
            #pragma unroll
            for (int ni = 0; ni < 4; ++ni)
                bfr[ni] = *reinterpret_cast<const bf16x8*>(
                    &Bs[(wn * 64 + ni * 16 + (lane & 15)) * 64 + kk * 32 + (lane >> 4) * 8]);
            #pragma unroll
            for (int mi = 0; mi < 4; ++mi)
                #pragma unroll
                for (int ni = 0; ni < 4; ++ni)
                    acc[mi][ni] = __builtin_amdgcn_mfma_f32_16x16x32_bf16(
                        af[mi], bfr[ni], acc[mi][ni], 0, 0, 0);
        }
        __syncthreads();
    }

    #pragma unroll
    for (int mi = 0; mi < 4; ++mi) {
        #pragma unroll
        for (int r = 0; r < 4; ++r) {
            int gm = m0 + wm * 64 + mi * 16 + (lane >> 4) * 4 + r;
            if (gm >= M) continue;
            int bq = gm / 197, sq = gm - bq * 197;
            #pragma unroll
            for (int ni = 0; ni < 4; ++ni) {
                int gn = n0 + wn * 64 + ni * 16 + (lane & 15);
                if (gn >= N) continue;
                float v = acc[mi][ni][r] + bias[gn];
                int c = gn >> 6, e = gn & 63;
                __hip_bfloat16 bv = __float2bfloat16(v);
                if (c == 0)      qb_[(long)gm * DD + zz * 64 + e] = bv;
                else if (c == 1) kb_[(long)gm * DD + zz * 64 + e] = bv;
                else             vtb[(((long)(bq * NHH + zz)) * 128 + e) * APAD + sq] = bv;
            }
        }
    }
}

// =====================================================================
// Fused flash attention: one block per (b,h). 4 waves x 256 threads.
// =====================================================================
__global__ __launch_bounds__(256) void attn_flash(
    const __hip_bfloat16* __restrict__ qbuf,
    const __hip_bfloat16* __restrict__ kbuf,
    const __hip_bfloat16* __restrict__ vt,   // [(b*12+h)*128 + e][APAD]
    __hip_bfloat16* __restrict__ ctx)        // [PADM][768]
{
    constexpr int KLD = 72;    // K lds row stride (elems)
    constexpr int VLD = 232;   // Vt lds row stride
    constexpr int PLD = 232;   // P lds row stride
    __shared__ __hip_bfloat16 Kl[208 * KLD];     // 29952 B
    __shared__ __hip_bfloat16 Vl[64 * VLD];      // 29696 B
    __shared__ __hip_bfloat16 Pl[4][16 * PLD];   // 29696 B

    const int h = blockIdx.x, b = blockIdx.y;
    const int t = threadIdx.x;
    const int w = t >> 6, lane = t & 63;
    const int l15 = lane & 15, g0 = lane >> 4;   // g0 in 0..3

    const long row0 = (long)b * 197;
    const int  hc   = h * 64;

    // ---- stage K: 208 rows x 8 groups of 8 elems
    for (int task = t; task < 208 * 8; task += 256) {
        int r = task >> 3, g = task & 7;
        float4 vv = *reinterpret_cast<const float4*>(kbuf + (row0 + r) * DD + hc + g * 8);
        *reinterpret_cast<float4*>(&Kl[r * KLD + g * 8]) = vv;
    }
    // ---- stage Vt: 64 rows x 28 groups (cols 0..223)
    const __hip_bfloat16* vsrc0 = vt + (long)(b * NHH + h) * 128 * APAD;
    for (int task = t; task < 64 * 32; task += 256) {
        int e = task >> 5, g = task & 31;
        if (g < 28) {
            float4 vv = *reinterpret_cast<const float4*>(vsrc0 + (long)e * APAD + g * 8);
            *reinterpret_cast<float4*>(&Vl[e * VLD + g * 8]) = vv;
        }
    }
    __syncthreads();

    __hip_bfloat16* Pw = Pl[w];

    for (int qc = w; qc < 13; qc += 4) {
        const int q0 = qc * 16;

        // ---- Q fragment (global; rows beyond TOK are poison-tiny, masked at store)
        const __hip_bfloat16* qsrc = qbuf + (row0 + q0 + l15) * DD + hc + g0 * 8;
        bf16x8 qf0 = *reinterpret_cast<const bf16x8*>(qsrc);
        bf16x8 qf1 = *reinterpret_cast<const bf16x8*>(qsrc + 32);

        // ---- QK^T: sacc[n] rows q=g0*4+r, cols k=n*16+l15
        f32x4 sacc[13];
        #pragma unroll
        for (int n = 0; n < 13; ++n) {
            bf16x8 kf0 = *reinterpret_cast<const bf16x8*>(&Kl[(n * 16 + l15) * KLD + g0 * 8]);
            bf16x8 kf1 = *reinterpret_cast<const bf16x8*>(&Kl[(n * 16 + l15) * KLD + 32 + g0 * 8]);
            f32x4 z = {0.f, 0.f, 0.f, 0.f};
            z = __builtin_amdgcn_mfma_f32_16x16x32_bf16(qf0, kf0, z, 0, 0, 0);
            sacc[n] = __builtin_amdgcn_mfma_f32_16x16x32_bf16(qf1, kf1, z, 0, 0, 0);
        }

        const int kcol = l15;   // k = n*16 + kcol
        float lrow[4];
        #pragma unroll
        for (int r = 0; r < 4; ++r) {
            float mx = -3.0e38f;
            #pragma unroll
            for (int n = 0; n < 13; ++n) {
                float s = sacc[n][r] * (1.0f / 4096.0f);
                if (n * 16 + kcol < 197) mx = fmaxf(mx, s);
            }
            #pragma unroll
            for (int off = 1; off < 16; off <<= 1) mx = fmaxf(mx, __shfl_xor(mx, off));
            float sum = 0.f;
            #pragma unroll
            for (int n = 0; n < 14; ++n) {
                float p = 0.f;
                if (n < 13 && n * 16 + kcol < 197) {
                    p = __expf(sacc[n][r] * (1.0f / 4096.0f) - mx);
                    sum += p;
                }
                Pw[(g0 * 4 + r) * PLD + n * 16 + kcol] = __float2bfloat16(p);
            }
            #pragma unroll
            for (int off = 1; off < 16; off <<= 1) sum += __shfl_xor(sum, off);
            lrow[r] = sum;
        }

        asm volatile("s_waitcnt lgkmcnt(0)" ::: "memory");

        // ---- PV: K-dim 224 (7 chunks of 32); A=P~ rows q=l15, B=Vt rows e
        f32x4 pv[4] = {};
        #pragma unroll
        for (int kc = 0; kc < 7; ++kc) {
            bf16x8 pf = *reinterpret_cast<const bf16x8*>(&Pw[l15 * PLD + kc * 32 + g0 * 8]);
            #pragma unroll
            for (int ni = 0; ni < 4; ++ni) {
                bf16x8 vf = *reinterpret_cast<const bf16x8*>(&Vl[(ni * 16 + l15) * VLD + kc * 32 + g0 * 8]);
                pv[ni] = __builtin_amdgcn_mfma_f32_16x16x32_bf16(pf, vf, pv[ni], 0, 0, 0);
            }
        }

        // ---- ctx = PV / l
        #pragma unroll
        for (int r = 0; r < 4; ++r) {
            int q = q0 + g0 * 4 + r;
            if (q >= 197) continue;
            float inv = 1.0f / lrow[r];
            #pragma unroll
            for (int ni = 0; ni < 4; ++ni)
                ctx[(row0 + q) * DD + hc + ni * 16 + l15] = __float2bfloat16(pv[ni][r] * inv);
        }
    }
}

// ---------------- LayerNorm: fp32 in, bf16 out ----------------
__global__ __launch_bounds__(256) void ln_kernel(
    const float* __restrict__ X, const float* __restrict__ g,
    const float* __restrict__ b, __hip_bfloat16* __restrict__ H)
{
    const long row = blockIdx.x;
    const float* x = X + row * DD;
    const int t = threadIdx.x;
    float v[3];
    float s = 0.f, s2 = 0.f;
    #pragma unroll
    for (int i = 0; i < 3; ++i) {
        v[i] = x[t + i * 256];
        s += v[i]; s2 += v[i] * v[i];
    }
    #pragma unroll
    for (int off = 1; off < 64; off <<= 1) {
        s  += __shfl_xor(s,  off);
        s2 += __shfl_xor(s2, off);
    }
    __shared__ float red[2][4];
    const int lane = t & 63, w = t >> 6;
    if (lane == 0) { red[0][w] = s; red[1][w] = s2; }
    __syncthreads();
    float S1 = red[0][0] + red[0][1] + red[0][2] + red[0][3];
    float S2 = red[1][0] + red[1][1] + red[1][2] + red[1][3];
    float mu  = S1 * (1.0f / 768.0f);
    float var = S2 * (1.0f / 768.0f) - mu * mu;
    float rs  = rsqrtf(var + 1e-5f);
    __hip_bfloat16* h = H + row * DD;
    #pragma unroll
    for (int i = 0; i < 3; ++i) {
        int c = t + i * 256;
        h[c] = __float2bfloat16((v[i] - mu) * rs * g[c] + b[c]);
    }
}

// ---------------- patchify: [B,C,H,W] f32 -> [B*196, 768] bf16 ----------------
__global__ void patchify_kernel(const float* __restrict__ img, __hip_bfloat16* __restrict__ patches)
{
    long idx = (long)blockIdx.x * 256 + threadIdx.x;
    const long total = (long)NB * NPAT * DD;
    if (idx >= total) return;
    int k  = (int)(idx % DD);
    long mp = idx / DD;
    int p  = (int)(mp % NPAT);
    long b = mp / NPAT;
    int c = k >> 8;
    int i = (k >> 4) & 15;
    int j = k & 15;
    int pr = p / 14, pc = p % 14;
    int hh = pr * 16 + i, ww = pc * 16 + j;
    patches[idx] = __float2bfloat16(img[((b * 3 + c) * 224 + hh) * 224 + ww]);
}

// ---------------- assemble x = concat(cls, tokens) + pos (fp32) ----------------
__global__ void assemble_kernel(const float* __restrict__ tok, const float* __restrict__ cls,
                                const float* __restrict__ pos, float* __restrict__ X)
{
    long idx = (long)blockIdx.x * 256 + threadIdx.x;
    if (idx >= NX) return;
    int d  = (int)(idx % DD);
    long bs = idx / DD;
    int s  = (int)(bs % SS);
    long b = bs / SS;
    float v = (s == 0) ? cls[d] : tok[(b * NPAT + s - 1) * DD + d];
    X[idx] = v + pos[(long)s * DD + d];
}

// ---------------- fp32 -> bf16 conversion (n multiple of 4) ----------------
__global__ void f2b_kernel(const float* __restrict__ src, __hip_bfloat16* __restrict__ dst, long n4)
{
    long i = (long)blockIdx.x * 256 + threadIdx.x;
    if (i >= n4) return;
    float4 v = *reinterpret_cast<const float4*>(&src[i * 4]);
    __hip_bfloat16 o[4] = { __float2bfloat16(v.x), __float2bfloat16(v.y),
                            __float2bfloat16(v.z), __float2bfloat16(v.w) };
    *reinterpret_cast<uint2*>(&dst[i * 4]) = *reinterpret_cast<const uint2*>(o);
}

// ---------------- pack per-head qkv weights ----------------
__global__ void qkvpack_kernel(const float* __restrict__ qw, const float* __restrict__ kw,
                               const float* __restrict__ vw, const float* __restrict__ qb,
                               const float* __restrict__ kb, const float* __restrict__ vb,
                               __hip_bfloat16* __restrict__ W, float* __restrict__ Bv)
{
    int idx = blockIdx.x * 256 + threadIdx.x;   // over 12*192*64
    if (idx >= NHH * 192 * 64) return;
    int d = idx & 63;
    int rest = idx >> 6;
    int j = rest % 192;
    int h = rest / 192;
    int c = j >> 6, e = j & 63;
    const float* src = (c == 0 ? qw : c == 1 ? kw : vw) + ((long)h * 64 + e) * 64 + d;
    W[((long)h * 256 + j) * 64 + d] = __float2bfloat16(*src);
    if (d == 0) {
        const float* sb = (c == 0 ? qb : c == 1 ? kb : vb) + h * 64 + e;
        Bv[h * 192 + j] = *sb;
    }
}

// ---------------- host ----------------
extern "C" void kernel_launch(void* const* d_in, const int* in_sizes, int n_in,
                              void* d_out, int out_size, void* d_ws, size_t ws_size,
                              hipStream_t stream)
{
    const float* images   = (const float*)d_in[0];
    const float* mapper_w = (const float*)d_in[1];
    const float* mapper_b = (const float*)d_in[2];
    const float* cls      = (const float*)d_in[3];
    const float* pos      = (const float*)d_in[4];
    const float* ln1_g    = (const float*)d_in[5];
    const float* ln1_b    = (const float*)d_in[6];
    const float* qw       = (const float*)d_in[7];
    const float* qb       = (const float*)d_in[8];
    const float* kw       = (const float*)d_in[9];
    const float* kb       = (const float*)d_in[10];
    const float* vw       = (const float*)d_in[11];
    const float* vb       = (const float*)d_in[12];
    const float* ow       = (const float*)d_in[13];
    const float* ob       = (const float*)d_in[14];
    const float* ln2_g    = (const float*)d_in[15];
    const float* ln2_b    = (const float*)d_in[16];
    const float* w1       = (const float*)d_in[17];
    const float* b1       = (const float*)d_in[18];
    const float* w2       = (const float*)d_in[19];
    const float* b2       = (const float*)d_in[20];
    float* out = (float*)d_out;

    // ---- workspace (bump allocator, 256B aligned)
    char* p0 = (char*)d_ws;
    char* pp = p0;
    auto alloc = [&](size_t bytes) { char* r = pp; pp += (bytes + 255) & ~(size_t)255; return r; };

    float*           x      = (float*)          alloc(NX * 4);
    __hip_bfloat16*  h16    = (__hip_bfloat16*) alloc((size_t)PADM2 * DD * 2);
    __hip_bfloat16*  ctx16  = (__hip_bfloat16*) alloc((size_t)PADM2 * DD * 2);
    __hip_bfloat16*  wbuf16 = (__hip_bfloat16*) alloc((size_t)(DD*DD + (size_t)FFF*DD*2) * 2);
    __hip_bfloat16*  wqkv16 = (__hip_bfloat16*) alloc((size_t)NHH * 256 * 64 * 2);
    float*           bqkv   = (float*)          alloc((size_t)NHH * 192 * 4);
    __hip_bfloat16*  qbuf   = (__hip_bfloat16*) alloc((size_t)PADM * DD * 2);
    __hip_bfloat16*  kbuf   = (__hip_bfloat16*) alloc((size_t)PADM * DD * 2);
    __hip_bfloat16*  vt     = (__hip_bfloat16*) alloc((size_t)NB * NHH * 128 * APAD * 2);
    // shared region: mid16 (78.6MB) | patches+tokens (57.9MB)
    char*            big    = alloc((size_t)PADM2 * FFF * 2);

    if ((size_t)(pp - p0) > ws_size) return;

    __hip_bfloat16* mid16     = (__hip_bfloat16*)big;
    __hip_bfloat16* patches16 = (__hip_bfloat16*)big;
    float*          tokens    = (float*)(big + (((size_t)NB * NPAT * DD * 2 + 255) & ~(size_t)255));

    __hip_bfloat16* ow16 = wbuf16;
    __hip_bfloat16* w116 = wbuf16 + (size_t)DD * DD;
    __hip_bfloat16* w216 = w116 + (size_t)FFF * DD;

    // ---- setup: patchify + mapper (256-tile MFMA) + assemble
    {
        long n = (long)NB * NPAT * DD;
        patchify_kernel<<<dim3((n + 255) / 256), dim3(256), 0, stream>>>(images, patches16);
        f2b_kernel<<<dim3((DD * DD / 4 + 255) / 256), dim3(256), 0, stream>>>(mapper_w, w116, DD * DD / 4);
        gemm_mfma256<0, false><<<dim3(DD / 256, (NB * NPAT) / 256), dim3(512), 0, stream>>>(
            patches16, DD, w116, DD, tokens, DD, mapper_b, nullptr, 0, nullptr,
            NB * NPAT, DD, DD);
        assemble_kernel<<<dim3((NX + 255) / 256), dim3(256), 0, stream>>>(tokens, cls, pos, x);
    }

    const int MT  = (TOK + 127) / 128;   // 99
    const int MT2 = (TOK + 255) / 256;   // 50

    for (int l = 0; l < 12; ++l) {
        // ---- weight prep for this layer
        f2b_kernel<<<dim3((DD * DD / 4 + 255) / 256), dim3(256), 0, stream>>>(
            ow + (long)l * DD * DD, ow16, DD * DD / 4);
        f2b_kernel<<<dim3((FFF * DD / 4 + 255) / 256), dim3(256), 0, stream>>>(
            w1 + (long)l * FFF * DD, w116, FFF * DD / 4);
        f2b_kernel<<<dim3((FFF * DD / 4 + 255) / 256), dim3(256), 0, stream>>>(
            w2 + (long)l * FFF * DD, w216, FFF * DD / 4);
        qkvpack_kernel<<<dim3((NHH * 192 * 64 + 255) / 256), dim3(256), 0, stream>>>(
            qw + (long)l * NHH * DHH * DHH, kw + (long)l * NHH * DHH * DHH,
            vw + (long)l * NHH * DHH * DHH,
            qb + (long)l * DD, kb + (long)l * DD, vb + (long)l * DD,
            wqkv16, bqkv);

        // ---- LN1 -> h16
        ln_kernel<<<dim3(TOK), dim3(256), 0, stream>>>(x, ln1_g + l * DD, ln1_b + l * DD, h16);

        // ---- QKV (q,k row-major; v transposed into vt); per-head A offset = 64 elems
        gemm_qkv<<<dim3(2, MT, NHH), dim3(256), 0, stream>>>(
            h16, DD, 64,
            wqkv16, 64, (long)256 * 64,
            bqkv, 192,
            qbuf, kbuf, vt,
            TOK, 192, 64);

        // ---- fused attention (scores+softmax+PV)
        attn_flash<<<dim3(NHH, NB), dim3(256), 0, stream>>>(qbuf, kbuf, vt, ctx16);

        // ---- x = x + ctx @ ow^T + ob  (256-tile)
        gemm_mfma256<1, false><<<dim3(DD / 256, MT2), dim3(512), 0, stream>>>(
            ctx16, DD, ow16, DD, x, DD, ob + l * DD, x, DD, nullptr,
            TOK, DD, DD);

        // ---- LN2 -> h16
        ln_kernel<<<dim3(TOK), dim3(256), 0, stream>>>(x, ln2_g + l * DD, ln2_b + l * DD, h16);

        // ---- mid = gelu(h @ w1^T + b1)  (256-tile)
        gemm_mfma256<2, true><<<dim3(FFF / 256, MT2), dim3(512), 0, stream>>>(
            h16, DD, w116, DD, mid16, FFF, b1 + l * FFF, nullptr, 0, nullptr,
            TOK, FFF, DD);

        // ---- x = x + mid @ w2^T + b2 (+ fused extraction)  (256-tile)
        int slot = (l == 2) ? 0 : (l == 5) ? 1 : (l == 8) ? 2 : (l == 11) ? 3 : -1;
        float* o2 = (slot >= 0) ? out + (long)slot * NX : nullptr;
        gemm_mfma256<1, false><<<dim3(DD / 256, MT2), dim3(512), 0, stream>>>(
            mid16, FFF, w216, FFF, x, DD, b2 + l * DD, x, DD, o2,
            TOK, DD, FFF);
    }
}

// Round 8
// 5432.820 us; speedup vs baseline: 5.4065x; 1.2352x over previous
//
#include <hip/hip_runtime.h>
#include <hip/hip_bf16.h>
#include <math.h>

// ---------------- problem constants ----------------
static constexpr int NB   = 64;           // batch
static constexpr int SS   = 197;          // tokens
static constexpr int DD   = 768;          // hidden
static constexpr int NHH  = 12;           // heads
static constexpr int DHH  = 64;           // head dim
static constexpr int FFF  = 3072;         // mlp hidden
static constexpr int TOK  = NB * SS;      // 12608
static constexpr int NPAT = 196;          // patches per image
static constexpr int PADM = 12672;        // TOK padded to multiple of 128
static constexpr int PADM2= 12800;        // TOK padded to multiple of 256
static constexpr long NX  = (long)TOK * DD;  // 9,682,944
static constexpr int APAD = 256;          // vt row pitch (k-slots)

typedef __attribute__((ext_vector_type(8))) short bf16x8;
typedef __attribute__((ext_vector_type(4))) float f32x4;

__device__ inline void gll16(const __hip_bfloat16* g, __hip_bfloat16* l) {
    __builtin_amdgcn_global_load_lds(
        (const __attribute__((address_space(1))) void*)g,
        (__attribute__((address_space(3))) void*)l, 16, 0, 0);
}

// =====================================================================
// 128x128 tile bf16 MFMA GEMM, BK=32, 4 waves (2Mx2N, wave-tile 64x64),
// double-buffered LDS (32 KiB), 2-phase K-loop, counted vmcnt(4),
// XOR bank-swizzle (g ^= (row>>1)&3), setprio, XCD-swizzled grid.
// C = A[M][K] * Bt[N][K]^T (+bias[n]) (+residual) (gelu)
// Requires: N mult of 128, K mult of 32 (>=64); A rows readable to
// next multiple of 128 (caller pads buffers); stores masked by M.
// EPI: 0 none, 1 +residual (opt dup-store out2), 2 gelu
// =====================================================================
template<int EPI, bool OUTBF>
__global__ __launch_bounds__(256, 4) void gemm128(
    const __hip_bfloat16* __restrict__ A, int lda,
    const __hip_bfloat16* __restrict__ Bt, int ldb,
    void* __restrict__ Cout, int ldc,
    const float* __restrict__ bias,
    const float* __restrict__ Rm, int ldr,
    float* __restrict__ out2,
    int M, int N, int K)
{
    __shared__ __hip_bfloat16 sh[2][2][128 * 32];   // [buf][A|B], 32 KiB total

    // ---- bijective XCD swizzle on flattened grid
    const int nbx = gridDim.x;
    const int nwg = nbx * gridDim.y;
    int flat = blockIdx.y * nbx + blockIdx.x;
    {
        int q = nwg >> 3, r = nwg & 7;
        int xcd = flat & 7, idx = flat >> 3;
        flat = (xcd < r ? xcd * (q + 1) : r * (q + 1) + (xcd - r) * q) + idx;
    }
    const int m0 = (flat / nbx) * 128;
    const int n0 = (flat % nbx) * 128;

    const int t = threadIdx.x;
    const int wid = t >> 6, lane = t & 63;
    const int wm = wid >> 1, wn = wid & 1;
    const int l15 = lane & 15, g0 = lane >> 4;
    const int rcol = ((g0 ^ ((l15 >> 1) & 3)) * 8);   // swizzled read col (elems)

    // staging: thread covers (row = j*64 + (t>>2), group = t&3), lane-linear dest
    const int srl = t >> 2, sg = t & 3;

    auto stage = [&](int buf, int k0) {
        #pragma unroll
        for (int j = 0; j < 2; ++j) {
            int row = j * 64 + srl;
            int gs = sg ^ ((row >> 1) & 3);           // inverse-swizzled source
            gll16(A + (long)(m0 + row) * lda + k0 + gs * 8,
                  &sh[buf][0][row * 32 + sg * 8]);
        }
        #pragma unroll
        for (int j = 0; j < 2; ++j) {
            int row = j * 64 + srl;
            int gs = sg ^ ((row >> 1) & 3);
            gll16(Bt + (long)(n0 + row) * ldb + k0 + gs * 8,
                  &sh[buf][1][row * 32 + sg * 8]);
        }
    };

    f32x4 acc[4][4] = {};
    const int NT = K >> 5;

    // ---- prologue: stage tiles 0,1 (4+4 loads/thread); tile0 must land
    stage(0, 0);
    stage(1, 32);
    asm volatile("s_waitcnt vmcnt(4)" ::: "memory");
    __builtin_amdgcn_sched_barrier(0);
    __builtin_amdgcn_s_barrier();
    __builtin_amdgcn_sched_barrier(0);

    for (int kt = 0; kt < NT; ++kt) {
        const int cur = kt & 1;
        const bool st2 = (kt + 2 < NT);
        const bool w1n = (kt + 1 < NT);

        // phase A: fragment reads from buf[cur]
        bf16x8 af[4], bfr[4];
        #pragma unroll
        for (int mi = 0; mi < 4; ++mi)
            af[mi] = *reinterpret_cast<const bf16x8*>(
                &sh[cur][0][(wm * 64 + mi * 16 + l15) * 32 + rcol]);
        #pragma unroll
        for (int ni = 0; ni < 4; ++ni)
            bfr[ni] = *reinterpret_cast<const bf16x8*>(
                &sh[cur][1][(wn * 64 + ni * 16 + l15) * 32 + rcol]);
        asm volatile("s_waitcnt lgkmcnt(0)" ::: "memory");
        __builtin_amdgcn_sched_barrier(0);
        __builtin_amdgcn_s_barrier();       // block-wide: buf[cur] fully read
        __builtin_amdgcn_sched_barrier(0);

        // phase B: refill buf[cur] with tile kt+2; MFMA; counted wait
        if (st2) stage(cur, (kt + 2) << 5);
        __builtin_amdgcn_s_setprio(1);
        #pragma unroll
        for (int mi = 0; mi < 4; ++mi)
            #pragma unroll
            for (int ni = 0; ni < 4; ++ni)
                acc[mi][ni] = __builtin_amdgcn_mfma_f32_16x16x32_bf16(
                    af[mi], bfr[ni], acc[mi][ni], 0, 0, 0);
        __builtin_amdgcn_s_setprio(0);
        __builtin_amdgcn_sched_barrier(0);
        if (st2)      { asm volatile("s_waitcnt vmcnt(4)" ::: "memory"); }  // kt+1 landed
        else if (w1n) { asm volatile("s_waitcnt vmcnt(0)" ::: "memory"); }  // tail drain
        __builtin_amdgcn_sched_barrier(0);
        __builtin_amdgcn_s_barrier();
        __builtin_amdgcn_sched_barrier(0);
    }

    // ---- epilogue: C/D layout col=lane&15, row=(lane>>4)*4+r
    #pragma unroll
    for (int mi = 0; mi < 4; ++mi) {
        #pragma unroll
        for (int r = 0; r < 4; ++r) {
            int gm = m0 + wm * 64 + mi * 16 + (lane >> 4) * 4 + r;
            if (gm >= M) continue;
            #pragma unroll
            for (int ni = 0; ni < 4; ++ni) {
                int gn = n0 + wn * 64 + ni * 16 + (lane & 15);
                float v = acc[mi][ni][r];
                if (bias) v += bias[gn];
                if (EPI == 1) v += Rm[(long)gm * ldr + gn];
                if (EPI == 2) v = 0.5f * v * (1.0f + erff(v * 0.70710678118654752f));
                if (OUTBF) {
                    ((__hip_bfloat16*)Cout)[(long)gm * ldc + gn] = __float2bfloat16(v);
                } else {
                    ((float*)Cout)[(long)gm * ldc + gn] = v;
                    if (EPI == 1 && out2) out2[(long)gm * ldc + gn] = v;
                }
            }
        }
    }
}

// =====================================================================
// 128x128 tile MFMA GEMM — QKV projection with scatter epilogue (K=64)
// =====================================================================
__global__ __launch_bounds__(256) void gemm_qkv(
    const __hip_bfloat16* __restrict__ A, int lda, long sAlo,
    const __hip_bfloat16* __restrict__ Bt, int ldb, long sBhi,
    const float* __restrict__ bias, long sbhi,
    __hip_bfloat16* __restrict__ qb_, __hip_bfloat16* __restrict__ kb_,
    __hip_bfloat16* __restrict__ vtb,
    int M, int N, int K)
{
    __shared__ __hip_bfloat16 As[128 * 64];
    __shared__ __hip_bfloat16 Bs[128 * 64];

    const int zz = blockIdx.z;
    A  += zz * sAlo;
    Bt += zz * sBhi;
    bias += zz * sbhi;

    const int t = threadIdx.x;
    const int wid = t >> 6, lane = t & 63;
    const int wm = wid >> 1, wn = wid & 1;
    const int m0 = blockIdx.y * 128, n0 = blockIdx.x * 128;

    const int srow = t >> 3;
    const int scol = (t & 7) * 8;

    f32x4 acc[4][4] = {};

    for (int k0 = 0; k0 < K; k0 += 64) {
        #pragma unroll
        for (int i = 0; i < 4; ++i) {
            const __hip_bfloat16* ga = A + (long)(m0 + i * 32 + srow) * lda + k0 + scol;
            __hip_bfloat16* la = As + (i * 256 + wid * 64) * 8;
            gll16(ga, la);
            const __hip_bfloat16* gb = Bt + (long)(n0 + i * 32 + srow) * ldb + k0 + scol;
            __hip_bfloat16* lb = Bs + (i * 256 + wid * 64) * 8;
            gll16(gb, lb);
        }
        asm volatile("s_waitcnt vmcnt(0)" ::: "memory");
        __syncthreads();

        #pragma unroll
        for (int kk = 0; kk < 2; ++kk) {
            bf16x8 af[4], bfr[4];
            #pragma unroll
            for (int mi = 0; mi < 4; ++mi)
                af[mi] = *reinterpret_cast<const bf16x8*>(
                    &As[(wm * 64 + mi * 16 + (lane & 15)) * 64 + kk * 32 + (lane >> 4) * 8]);
            #pragma unroll
            for (int ni = 0; ni < 4; ++ni)
                bfr[ni] = *reinterpret_cast<const bf16x8*>(
                    &Bs[(wn * 64 + ni * 16 + (lane & 15)) * 64 + kk * 32 + (lane >> 4) * 8]);
            #pragma unroll
            for (int mi = 0; mi < 4; ++mi)
                #pragma unroll
                for (int ni = 0; ni < 4; ++ni)
                    acc[mi][ni] = __builtin_amdgcn_mfma_f32_16x16x32_bf16(
                        af[mi], bfr[ni], acc[mi][ni], 0, 0, 0);
        }
        __syncthreads();
    }

    #pragma unroll
    for (int mi = 0; mi < 4; ++mi) {
        #pragma unroll
        for (int r = 0; r < 4; ++r) {
            int gm = m0 + wm * 64 + mi * 16 + (lane >> 4) * 4 + r;
            if (gm >= M) continue;
            int bq = gm / 197, sq = gm - bq * 197;
            #pragma unroll
            for (int ni = 0; ni < 4; ++ni) {
                int gn = n0 + wn * 64 + ni * 16 + (lane & 15);
                if (gn >= N) continue;
                float v = acc[mi][ni][r] + bias[gn];
                int c = gn >> 6, e = gn & 63;
                __hip_bfloat16 bv = __float2bfloat16(v);
                if (c == 0)      qb_[(long)gm * DD + zz * 64 + e] = bv;
                else if (c == 1) kb_[(long)gm * DD + zz * 64 + e] = bv;
                else             vtb[(((long)(bq * NHH + zz)) * 128 + e) * APAD + sq] = bv;
            }
        }
    }
}

// =====================================================================
// Fused flash attention: one block per (b,h). 4 waves x 256 threads.
// =====================================================================
__global__ __launch_bounds__(256) void attn_flash(
    const __hip_bfloat16* __restrict__ qbuf,
    const __hip_bfloat16* __restrict__ kbuf,
    const __hip_bfloat16* __restrict__ vt,   // [(b*12+h)*128 + e][APAD]
    __hip_bfloat16* __restrict__ ctx)        // [PADM][768]
{
    constexpr int KLD = 72;    // K lds row stride (elems)
    constexpr int VLD = 232;   // Vt lds row stride
    constexpr int PLD = 232;   // P lds row stride
    __shared__ __hip_bfloat16 Kl[208 * KLD];     // 29952 B
    __shared__ __hip_bfloat16 Vl[64 * VLD];      // 29696 B
    __shared__ __hip_bfloat16 Pl[4][16 * PLD];   // 29696 B

    const int h = blockIdx.x, b = blockIdx.y;
    const int t = threadIdx.x;
    const int w = t >> 6, lane = t & 63;
    const int l15 = lane & 15, g0 = lane >> 4;   // g0 in 0..3

    const long row0 = (long)b * 197;
    const int  hc   = h * 64;

    // ---- stage K: 208 rows x 8 groups of 8 elems
    for (int task = t; task < 208 * 8; task += 256) {
        int r = task >> 3, g = task & 7;
        float4 vv = *reinterpret_cast<const float4*>(kbuf + (row0 + r) * DD + hc + g * 8);
        *reinterpret_cast<float4*>(&Kl[r * KLD + g * 8]) = vv;
    }
    // ---- stage Vt: 64 rows x 28 groups (cols 0..223)
    const __hip_bfloat16* vsrc0 = vt + (long)(b * NHH + h) * 128 * APAD;
    for (int task = t; task < 64 * 32; task += 256) {
        int e = task >> 5, g = task & 31;
        if (g < 28) {
            float4 vv = *reinterpret_cast<const float4*>(vsrc0 + (long)e * APAD + g * 8);
            *reinterpret_cast<float4*>(&Vl[e * VLD + g * 8]) = vv;
        }
    }
    __syncthreads();

    __hip_bfloat16* Pw = Pl[w];

    for (int qc = w; qc < 13; qc += 4) {
        const int q0 = qc * 16;

        const __hip_bfloat16* qsrc = qbuf + (row0 + q0 + l15) * DD + hc + g0 * 8;
        bf16x8 qf0 = *reinterpret_cast<const bf16x8*>(qsrc);
        bf16x8 qf1 = *reinterpret_cast<const bf16x8*>(qsrc + 32);

        // ---- QK^T: sacc[n] rows q=g0*4+r, cols k=n*16+l15
        f32x4 sacc[13];
        #pragma unroll
        for (int n = 0; n < 13; ++n) {
            bf16x8 kf0 = *reinterpret_cast<const bf16x8*>(&Kl[(n * 16 + l15) * KLD + g0 * 8]);
            bf16x8 kf1 = *reinterpret_cast<const bf16x8*>(&Kl[(n * 16 + l15) * KLD + 32 + g0 * 8]);
            f32x4 z = {0.f, 0.f, 0.f, 0.f};
            z = __builtin_amdgcn_mfma_f32_16x16x32_bf16(qf0, kf0, z, 0, 0, 0);
            sacc[n] = __builtin_amdgcn_mfma_f32_16x16x32_bf16(qf1, kf1, z, 0, 0, 0);
        }

        const int kcol = l15;   // k = n*16 + kcol
        float lrow[4];
        #pragma unroll
        for (int r = 0; r < 4; ++r) {
            float mx = -3.0e38f;
            #pragma unroll
            for (int n = 0; n < 13; ++n) {
                float s = sacc[n][r] * (1.0f / 4096.0f);
                if (n * 16 + kcol < 197) mx = fmaxf(mx, s);
            }
            #pragma unroll
            for (int off = 1; off < 16; off <<= 1) mx = fmaxf(mx, __shfl_xor(mx, off));
            float sum = 0.f;
            #pragma unroll
            for (int n = 0; n < 14; ++n) {
                float p = 0.f;
                if (n < 13 && n * 16 + kcol < 197) {
                    p = __expf(sacc[n][r] * (1.0f / 4096.0f) - mx);
                    sum += p;
                }
                Pw[(g0 * 4 + r) * PLD + n * 16 + kcol] = __float2bfloat16(p);
            }
            #pragma unroll
            for (int off = 1; off < 16; off <<= 1) sum += __shfl_xor(sum, off);
            lrow[r] = sum;
        }

        asm volatile("s_waitcnt lgkmcnt(0)" ::: "memory");

        // ---- PV: K-dim 224 (7 chunks of 32)
        f32x4 pv[4] = {};
        #pragma unroll
        for (int kc = 0; kc < 7; ++kc) {
            bf16x8 pf = *reinterpret_cast<const bf16x8*>(&Pw[l15 * PLD + kc * 32 + g0 * 8]);
            #pragma unroll
            for (int ni = 0; ni < 4; ++ni) {
                bf16x8 vf = *reinterpret_cast<const bf16x8*>(&Vl[(ni * 16 + l15) * VLD + kc * 32 + g0 * 8]);
                pv[ni] = __builtin_amdgcn_mfma_f32_16x16x32_bf16(pf, vf, pv[ni], 0, 0, 0);
            }
        }

        // ---- ctx = PV / l
        #pragma unroll
        for (int r = 0; r < 4; ++r) {
            int q = q0 + g0 * 4 + r;
            if (q >= 197) continue;
            float inv = 1.0f / lrow[r];
            #pragma unroll
            for (int ni = 0; ni < 4; ++ni)
                ctx[(row0 + q) * DD + hc + ni * 16 + l15] = __float2bfloat16(pv[ni][r] * inv);
        }
    }
}

// ---------------- LayerNorm: fp32 in, bf16 out ----------------
__global__ __launch_bounds__(256) void ln_kernel(
    const float* __restrict__ X, const float* __restrict__ g,
    const float* __restrict__ b, __hip_bfloat16* __restrict__ H)
{
    const long row = blockIdx.x;
    const float* x = X + row * DD;
    const int t = threadIdx.x;
    float v[3];
    float s = 0.f, s2 = 0.f;
    #pragma unroll
    for (int i = 0; i < 3; ++i) {
        v[i] = x[t + i * 256];
        s += v[i]; s2 += v[i] * v[i];
    }
    #pragma unroll
    for (int off = 1; off < 64; off <<= 1) {
        s  += __shfl_xor(s,  off);
        s2 += __shfl_xor(s2, off);
    }
    __shared__ float red[2][4];
    const int lane = t & 63, w = t >> 6;
    if (lane == 0) { red[0][w] = s; red[1][w] = s2; }
    __syncthreads();
    float S1 = red[0][0] + red[0][1] + red[0][2] + red[0][3];
    float S2 = red[1][0] + red[1][1] + red[1][2] + red[1][3];
    float mu  = S1 * (1.0f / 768.0f);
    float var = S2 * (1.0f / 768.0f) - mu * mu;
    float rs  = rsqrtf(var + 1e-5f);
    __hip_bfloat16* h = H + row * DD;
    #pragma unroll
    for (int i = 0; i < 3; ++i) {
        int c = t + i * 256;
        h[c] = __float2bfloat16((v[i] - mu) * rs * g[c] + b[c]);
    }
}

// ---------------- patchify: [B,C,H,W] f32 -> [B*196, 768] bf16 ----------------
__global__ void patchify_kernel(const float* __restrict__ img, __hip_bfloat16* __restrict__ patches)
{
    long idx = (long)blockIdx.x * 256 + threadIdx.x;
    const long total = (long)NB * NPAT * DD;
    if (idx >= total) return;
    int k  = (int)(idx % DD);
    long mp = idx / DD;
    int p  = (int)(mp % NPAT);
    long b = mp / NPAT;
    int c = k >> 8;
    int i = (k >> 4) & 15;
    int j = k & 15;
    int pr = p / 14, pc = p % 14;
    int hh = pr * 16 + i, ww = pc * 16 + j;
    patches[idx] = __float2bfloat16(img[((b * 3 + c) * 224 + hh) * 224 + ww]);
}

// ---------------- assemble x = concat(cls, tokens) + pos (fp32) ----------------
__global__ void assemble_kernel(const float* __restrict__ tok, const float* __restrict__ cls,
                                const float* __restrict__ pos, float* __restrict__ X)
{
    long idx = (long)blockIdx.x * 256 + threadIdx.x;
    if (idx >= NX) return;
    int d  = (int)(idx % DD);
    long bs = idx / DD;
    int s  = (int)(bs % SS);
    long b = bs / SS;
    float v = (s == 0) ? cls[d] : tok[(b * NPAT + s - 1) * DD + d];
    X[idx] = v + pos[(long)s * DD + d];
}

// ---------------- fp32 -> bf16 conversion (n multiple of 4) ----------------
__global__ void f2b_kernel(const float* __restrict__ src, __hip_bfloat16* __restrict__ dst, long n4)
{
    long i = (long)blockIdx.x * 256 + threadIdx.x;
    if (i >= n4) return;
    float4 v = *reinterpret_cast<const float4*>(&src[i * 4]);
    __hip_bfloat16 o[4] = { __float2bfloat16(v.x), __float2bfloat16(v.y),
                            __float2bfloat16(v.z), __float2bfloat16(v.w) };
    *reinterpret_cast<uint2*>(&dst[i * 4]) = *reinterpret_cast<const uint2*>(o);
}

// ---------------- fused 3-matrix fp32 -> bf16 (per layer: ow, w1, w2) ----------------
__global__ void f2b3_kernel(const float* __restrict__ s0, __hip_bfloat16* __restrict__ d0, long q0,
                            const float* __restrict__ s1, __hip_bfloat16* __restrict__ d1, long q1,
                            const float* __restrict__ s2, __hip_bfloat16* __restrict__ d2, long q2)
{
    long i = (long)blockIdx.x * 256 + threadIdx.x;
    const float* s; __hip_bfloat16* d;
    if (i < q0)           { s = s0; d = d0; }
    else if (i < q0 + q1) { s = s1; d = d1; i -= q0; }
    else if (i < q0 + q1 + q2) { s = s2; d = d2; i -= q0 + q1; }
    else return;
    float4 v = *reinterpret_cast<const float4*>(&s[i * 4]);
    __hip_bfloat16 o[4] = { __float2bfloat16(v.x), __float2bfloat16(v.y),
                            __float2bfloat16(v.z), __float2bfloat16(v.w) };
    *reinterpret_cast<uint2*>(&d[i * 4]) = *reinterpret_cast<const uint2*>(o);
}

// ---------------- pack per-head qkv weights ----------------
__global__ void qkvpack_kernel(const float* __restrict__ qw, const float* __restrict__ kw,
                               const float* __restrict__ vw, const float* __restrict__ qb,
                               const float* __restrict__ kb, const float* __restrict__ vb,
                               __hip_bfloat16* __restrict__ W, float* __restrict__ Bv)
{
    int idx = blockIdx.x * 256 + threadIdx.x;   // over 12*192*64
    if (idx >= NHH * 192 * 64) return;
    int d = idx & 63;
    int rest = idx >> 6;
    int j = rest % 192;
    int h = rest / 192;
    int c = j >> 6, e = j & 63;
    const float* src = (c == 0 ? qw : c == 1 ? kw : vw) + ((long)h * 64 + e) * 64 + d;
    W[((long)h * 256 + j) * 64 + d] = __float2bfloat16(*src);
    if (d == 0) {
        const float* sb = (c == 0 ? qb : c == 1 ? kb : vb) + h * 64 + e;
        Bv[h * 192 + j] = *sb;
    }
}

// ---------------- host ----------------
extern "C" void kernel_launch(void* const* d_in, const int* in_sizes, int n_in,
                              void* d_out, int out_size, void* d_ws, size_t ws_size,
                              hipStream_t stream)
{
    const float* images   = (const float*)d_in[0];
    const float* mapper_w = (const float*)d_in[1];
    const float* mapper_b = (const float*)d_in[2];
    const float* cls      = (const float*)d_in[3];
    const float* pos      = (const float*)d_in[4];
    const float* ln1_g    = (const float*)d_in[5];
    const float* ln1_b    = (const float*)d_in[6];
    const float* qw       = (const float*)d_in[7];
    const float* qb       = (const float*)d_in[8];
    const float* kw       = (const float*)d_in[9];
    const float* kb       = (const float*)d_in[10];
    const float* vw       = (const float*)d_in[11];
    const float* vb       = (const float*)d_in[12];
    const float* ow       = (const float*)d_in[13];
    const float* ob       = (const float*)d_in[14];
    const float* ln2_g    = (const float*)d_in[15];
    const float* ln2_b    = (const float*)d_in[16];
    const float* w1       = (const float*)d_in[17];
    const float* b1       = (const float*)d_in[18];
    const float* w2       = (const float*)d_in[19];
    const float* b2       = (const float*)d_in[20];
    float* out = (float*)d_out;

    // ---- workspace (bump allocator, 256B aligned)
    char* p0 = (char*)d_ws;
    char* pp = p0;
    auto alloc = [&](size_t bytes) { char* r = pp; pp += (bytes + 255) & ~(size_t)255; return r; };

    float*           x      = (float*)          alloc(NX * 4);
    __hip_bfloat16*  h16    = (__hip_bfloat16*) alloc((size_t)PADM2 * DD * 2);
    __hip_bfloat16*  ctx16  = (__hip_bfloat16*) alloc((size_t)PADM2 * DD * 2);
    __hip_bfloat16*  wbuf16 = (__hip_bfloat16*) alloc((size_t)(DD*DD + (size_t)FFF*DD*2) * 2);
    __hip_bfloat16*  wqkv16 = (__hip_bfloat16*) alloc((size_t)NHH * 256 * 64 * 2);
    float*           bqkv   = (float*)          alloc((size_t)NHH * 192 * 4);
    __hip_bfloat16*  qbuf   = (__hip_bfloat16*) alloc((size_t)PADM * DD * 2);
    __hip_bfloat16*  kbuf   = (__hip_bfloat16*) alloc((size_t)PADM * DD * 2);
    __hip_bfloat16*  vt     = (__hip_bfloat16*) alloc((size_t)NB * NHH * 128 * APAD * 2);
    // shared region: mid16 (78.6MB) | patches+tokens (57.9MB)
    char*            big    = alloc((size_t)PADM2 * FFF * 2);

    if ((size_t)(pp - p0) > ws_size) return;

    __hip_bfloat16* mid16     = (__hip_bfloat16*)big;
    __hip_bfloat16* patches16 = (__hip_bfloat16*)big;
    float*          tokens    = (float*)(big + (((size_t)NB * NPAT * DD * 2 + 255) & ~(size_t)255));

    __hip_bfloat16* ow16 = wbuf16;
    __hip_bfloat16* w116 = wbuf16 + (size_t)DD * DD;
    __hip_bfloat16* w216 = w116 + (size_t)FFF * DD;

    // ---- setup: patchify + mapper + assemble
    {
        long n = (long)NB * NPAT * DD;
        patchify_kernel<<<dim3((n + 255) / 256), dim3(256), 0, stream>>>(images, patches16);
        f2b_kernel<<<dim3((DD * DD / 4 + 255) / 256), dim3(256), 0, stream>>>(mapper_w, w116, DD * DD / 4);
        gemm128<0, false><<<dim3(DD / 128, (NB * NPAT) / 128), dim3(256), 0, stream>>>(
            patches16, DD, w116, DD, tokens, DD, mapper_b, nullptr, 0, nullptr,
            NB * NPAT, DD, DD);
        assemble_kernel<<<dim3((NX + 255) / 256), dim3(256), 0, stream>>>(tokens, cls, pos, x);
    }

    const int MT = (TOK + 127) / 128;   // 99
    const long Q1 = (long)DD * DD / 4, Q2 = (long)FFF * DD / 4;

    for (int l = 0; l < 12; ++l) {
        // ---- weight prep for this layer (fused)
        f2b3_kernel<<<dim3((int)((Q1 + 2 * Q2 + 255) / 256)), dim3(256), 0, stream>>>(
            ow + (long)l * DD * DD, ow16, Q1,
            w1 + (long)l * FFF * DD, w116, Q2,
            w2 + (long)l * FFF * DD, w216, Q2);
        qkvpack_kernel<<<dim3((NHH * 192 * 64 + 255) / 256), dim3(256), 0, stream>>>(
            qw + (long)l * NHH * DHH * DHH, kw + (long)l * NHH * DHH * DHH,
            vw + (long)l * NHH * DHH * DHH,
            qb + (long)l * DD, kb + (long)l * DD, vb + (long)l * DD,
            wqkv16, bqkv);

        // ---- LN1 -> h16
        ln_kernel<<<dim3(TOK), dim3(256), 0, stream>>>(x, ln1_g + l * DD, ln1_b + l * DD, h16);

        // ---- QKV (q,k row-major; v transposed into vt); per-head A offset = 64 elems
        gemm_qkv<<<dim3(2, MT, NHH), dim3(256), 0, stream>>>(
            h16, DD, 64,
            wqkv16, 64, (long)256 * 64,
            bqkv, 192,
            qbuf, kbuf, vt,
            TOK, 192, 64);

        // ---- fused attention (scores+softmax+PV)
        attn_flash<<<dim3(NHH, NB), dim3(256), 0, stream>>>(qbuf, kbuf, vt, ctx16);

        // ---- x = x + ctx @ ow^T + ob
        gemm128<1, false><<<dim3(DD / 128, MT), dim3(256), 0, stream>>>(
            ctx16, DD, ow16, DD, x, DD, ob + l * DD, x, DD, nullptr,
            TOK, DD, DD);

        // ---- LN2 -> h16
        ln_kernel<<<dim3(TOK), dim3(256), 0, stream>>>(x, ln2_g + l * DD, ln2_b + l * DD, h16);

        // ---- mid = gelu(h @ w1^T + b1)
        gemm128<2, true><<<dim3(FFF / 128, MT), dim3(256), 0, stream>>>(
            h16, DD, w116, DD, mid16, FFF, b1 + l * FFF, nullptr, 0, nullptr,
            TOK, FFF, DD);

        // ---- x = x + mid @ w2^T + b2 (+ fused extraction)
        int slot = (l == 2) ? 0 : (l == 5) ? 1 : (l == 8) ? 2 : (l == 11) ? 3 : -1;
        float* o2 = (slot >= 0) ? out + (long)slot * NX : nullptr;
        gemm128<1, false><<<dim3(DD / 128, MT), dim3(256), 0, stream>>>(
            mid16, FFF, w216, FFF, x, DD, b2 + l * DD, x, DD, o2,
            TOK, DD, FFF);
    }
}